// Round 2
// baseline (1331.272 us; speedup 1.0000x reference)
//
#include <hip/hip_runtime.h>
#include <hip/hip_bf16.h>
#include <math.h>

#define Q_TOT 43200
#define H_ 120
#define W_ 360

typedef unsigned short ushort_t;
typedef float f32x4 __attribute__((ext_vector_type(4)));
typedef unsigned short u16x4 __attribute__((ext_vector_type(4)));
typedef unsigned short u16x8 __attribute__((ext_vector_type(8)));

static __device__ __forceinline__ float b2f(unsigned short u){
  return __uint_as_float(((unsigned)u) << 16);
}
static __device__ __forceinline__ unsigned short f2b(float f){
  unsigned u = __float_as_uint(f);
  unsigned r = (u + 0x7fffu + ((u >> 16) & 1u)) >> 16;  // RNE
  return (unsigned short)r;
}

// ---------------- fp32 -> bf16 weight conversion (all 20 weight/bias arrays) ----
#define CVT_TOT 615072
__global__ __launch_bounds__(256) void cvt_kernel(
    const float* p0, const float* p1, const float* p2, const float* p3,
    const float* p4, const float* p5, const float* p6, const float* p7,
    const float* p8, const float* p9, const float* p10, const float* p11,
    const float* p12, const float* p13, const float* p14, const float* p15,
    const float* p16, const float* p17, const float* p18, const float* p19,
    ushort_t* __restrict__ dst){
  const float* ps[20] = {p0,p1,p2,p3,p4,p5,p6,p7,p8,p9,p10,p11,p12,p13,p14,p15,p16,p17,p18,p19};
  const int offs[20] = {0,65536,65664,90240,90432,102720,102816,151968,152352,201504,
                        201888,202272,202656,399264,400800,597408,597792,598176,598560,614944};
  int gid = blockIdx.x*256 + threadIdx.x;
  if (gid >= CVT_TOT) return;
  int s = 0;
  #pragma unroll
  for (int i=1;i<20;i++) s += (gid >= offs[i]) ? 1 : 0;
  dst[gid] = f2b(ps[s][gid - offs[s]]);
}

// ---------------- pos embedding ----------------
__global__ __launch_bounds__(256) void pos_kernel(float* __restrict__ pos){
  int idx = blockIdx.x*256 + threadIdx.x;          // < Q_TOT*128 exactly
  int q = idx >> 7, k = idx & 127;
  int qy = q / W_, qx = q - qy*W_;
  int kk = k & 63;
  float e;
  if (k < 64) e = (float)(qy+1) * (6.283185307179586f / ((float)H_ + 1e-6f));
  else        e = (float)(qx+1) * (6.283185307179586f / ((float)W_ + 1e-6f));
  int m = kk >> 1;
  float t = powf(10000.0f, (float)m * (1.0f/32.0f));
  float p = e / t;
  pos[idx] = (kk & 1) ? cosf(p) : sinf(p);
}

// ---------------- merge: src = relu(x^T @ merge_w^T + b), K=512, x fp32 ----------
__global__ __launch_bounds__(256) void merge_kernel(const float* __restrict__ x,
    const ushort_t* __restrict__ mw, const ushort_t* __restrict__ mb,
    float* __restrict__ src){
  __shared__ float xs[32][64];
  __shared__ float wls[32][128];
  const int tid = threadIdx.x;
  const int q0 = blockIdx.x * 64;
  const int tn = tid & 31, tm = tid >> 5;
  float acc[8][4];
  #pragma unroll
  for (int iq=0;iq<8;iq++)
    #pragma unroll
    for (int j=0;j<4;j++) acc[iq][j]=0.f;
  for (int k0 = 0; k0 < 512; k0 += 32){
    if (k0) __syncthreads();
    { // x tile [32 k][64 q], fp32 direct
      int kk = tid >> 3, m0 = (tid & 7) << 3;
      const float* xp = x + (size_t)(k0+kk)*Q_TOT + q0 + m0;
      f32x4 v0 = *(const f32x4*)xp;
      f32x4 v1 = *(const f32x4*)(xp + 4);
      *(f32x4*)&xs[kk][m0]   = v0;
      *(f32x4*)&xs[kk][m0+4] = v1;
    }
    { // w tile [32 k][128 d], transposed from mw[d][512] (bf16 copy)
      int d = tid >> 1, h16 = (tid & 1) << 4;
      u16x8 v0 = *(const u16x8*)(mw + d*512 + k0 + h16);
      u16x8 v1 = *(const u16x8*)(mw + d*512 + k0 + h16 + 8);
      #pragma unroll
      for (int i=0;i<8;i++) wls[h16+i][d] = b2f(v0[i]);
      #pragma unroll
      for (int i=0;i<8;i++) wls[h16+8+i][d] = b2f(v1[i]);
    }
    __syncthreads();
    for (int kk = 0; kk < 32; kk++){
      f32x4 w = *(const f32x4*)&wls[kk][tn<<2];
      f32x4 a0 = *(const f32x4*)&xs[kk][tm<<3];
      f32x4 a1 = *(const f32x4*)&xs[kk][(tm<<3)+4];
      #pragma unroll
      for (int j=0;j<4;j++){
        acc[0][j] += a0[0]*w[j]; acc[1][j] += a0[1]*w[j];
        acc[2][j] += a0[2]*w[j]; acc[3][j] += a0[3]*w[j];
        acc[4][j] += a1[0]*w[j]; acc[5][j] += a1[1]*w[j];
        acc[6][j] += a1[2]*w[j]; acc[7][j] += a1[3]*w[j];
      }
    }
  }
  float bb[4];
  #pragma unroll
  for (int j=0;j<4;j++) bb[j] = b2f(mb[(tn<<2)+j]);
  #pragma unroll
  for (int iq=0;iq<8;iq++){
    f32x4 r;
    #pragma unroll
    for (int j=0;j<4;j++){ float v = acc[iq][j] + bb[j]; r[j] = v > 0.f ? v : 0.f; }
    *(f32x4*)&src[(size_t)(q0 + (tm<<3) + iq)*128 + (tn<<2)] = r;
  }
}

// ---------------- off/aw: q=(src+pos) @ [off_w|aw_w], softmax, loc ----------------
__global__ __launch_bounds__(256) void offaw_kernel(const float* __restrict__ src,
    const float* __restrict__ pos,
    const ushort_t* __restrict__ ow, const ushort_t* __restrict__ ob,
    const ushort_t* __restrict__ aww, const ushort_t* __restrict__ awb,
    float* __restrict__ loc, float* __restrict__ awg){
  __shared__ float qs[64*128];       // 32KB, reused as raw[64][96] later
  __shared__ ushort_t wb_s[128*96];  // 24KB
  const int tid = threadIdx.x;
  const int q0 = blockIdx.x * 64;
  for (int i = tid*4; i < 64*128; i += 1024){
    f32x4 s = *(const f32x4*)&src[(size_t)q0*128 + i];
    f32x4 p = *(const f32x4*)&pos[(size_t)q0*128 + i];
    *(f32x4*)&qs[i] = s + p;
  }
  for (int i = tid*8; i < 128*64; i += 2048){
    u16x8 v = *(const u16x8*)&ow[i];
    *(u16x8*)&wb_s[(i >> 6)*96 + (i & 63)] = v;
  }
  for (int i = tid*8; i < 128*32; i += 2048){
    u16x8 v = *(const u16x8*)&aww[i];
    *(u16x8*)&wb_s[(i >> 5)*96 + 64 + (i & 31)] = v;
  }
  __syncthreads();
  const int tn = tid & 31, tm = tid >> 5;   // 3 cols/thread, 8 q/thread
  float acc[8][3];
  #pragma unroll
  for (int iq=0;iq<8;iq++)
    #pragma unroll
    for (int j=0;j<3;j++) acc[iq][j]=0.f;
  for (int k4 = 0; k4 < 32; k4++){
    float w[4][3];
    #pragma unroll
    for (int kk=0;kk<4;kk++)
      #pragma unroll
      for (int j=0;j<3;j++)
        w[kk][j] = b2f(wb_s[(k4*4+kk)*96 + tn*3 + j]);
    #pragma unroll
    for (int iq=0;iq<8;iq++){
      f32x4 a = *(const f32x4*)&qs[(tm*8+iq)*128 + k4*4];
      #pragma unroll
      for (int kk=0;kk<4;kk++)
        #pragma unroll
        for (int j=0;j<3;j++)
          acc[iq][j] += a[kk]*w[kk][j];
    }
  }
  __syncthreads();
  #pragma unroll
  for (int iq=0;iq<8;iq++)
    #pragma unroll
    for (int j=0;j<3;j++)
      qs[(tm*8+iq)*96 + tn*3 + j] = acc[iq][j];
  __syncthreads();
  for (int u = tid; u < 512; u += 256){   // (q_local, head)
    int qi = u >> 3, h = u & 7;
    int q = q0 + qi;
    const float* rw = &qs[qi*96];
    float av[4], mx = -1e30f;
    #pragma unroll
    for (int p=0;p<4;p++){ av[p] = rw[64 + h*4 + p] + b2f(awb[h*4+p]); mx = fmaxf(mx, av[p]); }
    float s = 0.f;
    #pragma unroll
    for (int p=0;p<4;p++){ av[p] = expf(av[p]-mx); s += av[p]; }
    float inv = 1.f/s;
    float qxf = (float)(q % W_);
    float qyf = (float)(q / W_);
    #pragma unroll
    for (int p=0;p<4;p++){
      awg[(size_t)q*32 + h*4 + p] = av[p]*inv;
      // x = loc_x*W - 0.5 = qx + off_x  (the 0.5s cancel)
      float ox = rw[h*8 + p*2]     + b2f(ob[h*8 + p*2]);
      float oy = rw[h*8 + p*2 + 1] + b2f(ob[h*8 + p*2 + 1]);
      loc[(size_t)q*64 + h*8 + p*2]     = qxf + ox;
      loc[(size_t)q*64 + h*8 + p*2 + 1] = qyf + oy;
    }
  }
}

// ---------------- val = src @ val_w + b (K=128,N=128) ----------------
__global__ __launch_bounds__(256) void val_kernel(const float* __restrict__ A,
    const ushort_t* __restrict__ Wg, const ushort_t* __restrict__ bias,
    float* __restrict__ outv){
  __shared__ float as[64*128];
  __shared__ ushort_t wsb[128*128];
  const int tid = threadIdx.x;
  const int q0 = blockIdx.x * 64;
  for (int i = tid*8; i < 128*128; i += 2048)
    *(u16x8*)&wsb[i] = *(const u16x8*)&Wg[i];
  for (int i = tid*4; i < 64*128; i += 1024)
    *(f32x4*)&as[i] = *(const f32x4*)&A[(size_t)q0*128 + i];
  __syncthreads();
  const int tn = tid & 31, tm = tid >> 5;
  float acc[8][4];
  #pragma unroll
  for (int iq=0;iq<8;iq++)
    #pragma unroll
    for (int j=0;j<4;j++) acc[iq][j]=0.f;
  for (int k4 = 0; k4 < 32; k4++){
    float w[4][4];
    #pragma unroll
    for (int kk=0;kk<4;kk++){
      u16x4 wu = *(const u16x4*)&wsb[(k4*4+kk)*128 + tn*4];
      #pragma unroll
      for (int j=0;j<4;j++) w[kk][j] = b2f(wu[j]);
    }
    #pragma unroll
    for (int iq=0;iq<8;iq++){
      f32x4 a = *(const f32x4*)&as[(tm*8+iq)*128 + k4*4];
      #pragma unroll
      for (int kk=0;kk<4;kk++)
        #pragma unroll
        for (int j=0;j<4;j++)
          acc[iq][j] += a[kk]*w[kk][j];
    }
  }
  f32x4 bb;
  #pragma unroll
  for (int j=0;j<4;j++) bb[j] = b2f(bias[tn*4+j]);
  #pragma unroll
  for (int iq=0;iq<8;iq++){
    f32x4 r;
    #pragma unroll
    for (int j=0;j<4;j++) r[j] = acc[iq][j] + bb[j];
    *(f32x4*)&outv[(size_t)(q0 + tm*8 + iq)*128 + tn*4] = r;
  }
}

// ---------------- deformable bilinear sampling + head-weighted sum ----------------
__global__ __launch_bounds__(256) void sample_kernel(const float* __restrict__ val,
    const float* __restrict__ loc, const float* __restrict__ awg,
    float* __restrict__ o){
  __shared__ float sl[2][64];
  __shared__ float sa[2][32];
  const int tid = threadIdx.x;
  const int q0 = blockIdx.x * 2;
  if (tid < 128){ sl[tid>>6][tid&63] = loc[(size_t)q0*64 + tid]; }
  else if (tid < 192){ int t = tid-128; sa[t>>5][t&31] = awg[(size_t)q0*32 + t]; }
  __syncthreads();
  const int ql = tid >> 7, c = tid & 127;
  const int h = c >> 4;
  float acc = 0.f;
  #pragma unroll
  for (int p=0;p<4;p++){
    float x = sl[ql][h*8 + p*2];
    float y = sl[ql][h*8 + p*2 + 1];
    float wgt = sa[ql][h*4 + p];
    float x0f = floorf(x), y0f = floorf(y);
    float wx = x - x0f, wy = y - y0f;
    int ix = (int)x0f, iy = (int)y0f;
    float s = 0.f;
    #pragma unroll
    for (int dy=0;dy<2;dy++){
      int yy = iy + dy;
      if (yy < 0 || yy >= H_) continue;
      float wyv = dy ? wy : 1.f - wy;
      #pragma unroll
      for (int dx=0;dx<2;dx++){
        int xx = ix + dx;
        if (xx < 0 || xx >= W_) continue;
        float wxv = dx ? wx : 1.f - wx;
        s += wyv*wxv*val[(size_t)(yy*W_ + xx)*128 + c];
      }
    }
    acc += wgt * s;
  }
  o[(size_t)(q0+ql)*128 + c] = acc;
}

// ---------------- out-proj + residual + LN, in-place on src ----------------
__global__ __launch_bounds__(256) void outln_kernel(const float* __restrict__ A,
    const ushort_t* __restrict__ Wg, const ushort_t* __restrict__ bias,
    const ushort_t* __restrict__ gs, const ushort_t* __restrict__ gb,
    float* __restrict__ src){
  __shared__ float as[64*128];
  __shared__ ushort_t wsb[128*128];
  const int tid = threadIdx.x;
  const int q0 = blockIdx.x * 64;
  for (int i = tid*8; i < 128*128; i += 2048)
    *(u16x8*)&wsb[i] = *(const u16x8*)&Wg[i];
  for (int i = tid*4; i < 64*128; i += 1024)
    *(f32x4*)&as[i] = *(const f32x4*)&A[(size_t)q0*128 + i];
  __syncthreads();
  const int tn = tid & 31, tm = tid >> 5;
  float acc[8][4];
  #pragma unroll
  for (int iq=0;iq<8;iq++)
    #pragma unroll
    for (int j=0;j<4;j++) acc[iq][j]=0.f;
  for (int k4 = 0; k4 < 32; k4++){
    float w[4][4];
    #pragma unroll
    for (int kk=0;kk<4;kk++){
      u16x4 wu = *(const u16x4*)&wsb[(k4*4+kk)*128 + tn*4];
      #pragma unroll
      for (int j=0;j<4;j++) w[kk][j] = b2f(wu[j]);
    }
    #pragma unroll
    for (int iq=0;iq<8;iq++){
      f32x4 a = *(const f32x4*)&as[(tm*8+iq)*128 + k4*4];
      #pragma unroll
      for (int kk=0;kk<4;kk++)
        #pragma unroll
        for (int j=0;j<4;j++)
          acc[iq][j] += a[kk]*w[kk][j];
    }
  }
  f32x4 g4, b4, bias4;
  #pragma unroll
  for (int j=0;j<4;j++){ g4[j]=b2f(gs[tn*4+j]); b4[j]=b2f(gb[tn*4+j]); bias4[j]=b2f(bias[tn*4+j]); }
  #pragma unroll
  for (int iq=0;iq<8;iq++){
    int q = q0 + tm*8 + iq;
    f32x4 r = *(const f32x4*)&src[(size_t)q*128 + tn*4];
    #pragma unroll
    for (int j=0;j<4;j++) r[j] += acc[iq][j] + bias4[j];
    float s1 = r[0]+r[1]+r[2]+r[3];
    float s2 = r[0]*r[0]+r[1]*r[1]+r[2]*r[2]+r[3]*r[3];
    #pragma unroll
    for (int off=16; off>0; off>>=1){
      s1 += __shfl_xor(s1, off, 64);
      s2 += __shfl_xor(s2, off, 64);
    }
    float mean = s1*(1.f/128.f);
    float var = s2*(1.f/128.f) - mean*mean;
    float inv = rsqrtf(var + 1e-5f);
    f32x4 outv;
    #pragma unroll
    for (int j=0;j<4;j++) outv[j] = (r[j]-mean)*inv*g4[j] + b4[j];
    *(f32x4*)&src[(size_t)q*128 + tn*4] = outv;
  }
}

// ---------------- fused FFN + residual + LN, in-place on src ----------------
__global__ __launch_bounds__(256) void ffn_kernel(
    const ushort_t* __restrict__ w1, const ushort_t* __restrict__ b1,
    const ushort_t* __restrict__ w2, const ushort_t* __restrict__ b2,
    const ushort_t* __restrict__ gs, const ushort_t* __restrict__ gb,
    float* __restrict__ src){
  __shared__ float ss[16][128];   // 8KB
  __shared__ float hs[16][512];   // 32KB
  const int tid = threadIdx.x;
  const int q0 = blockIdx.x * 16;
  for (int i = tid*4; i < 16*128; i += 1024)
    *(f32x4*)&ss[0][i] = *(const f32x4*)&src[(size_t)q0*128 + i];
  __syncthreads();
  { // phase 1: h = relu(ss @ w1 + b1); 2 cols/thread
    const int n0 = tid*2;
    float acc0[16], acc1[16];
    #pragma unroll
    for (int i=0;i<16;i++){ acc0[i]=0.f; acc1[i]=0.f; }
    for (int k4 = 0; k4 < 32; k4++){
      float wa[4], wbv[4];
      #pragma unroll
      for (int kk=0;kk<4;kk++){
        unsigned wu = *(const unsigned*)&w1[(size_t)(k4*4+kk)*512 + n0];
        wa[kk]  = __uint_as_float(wu << 16);
        wbv[kk] = __uint_as_float(wu & 0xffff0000u);
      }
      #pragma unroll
      for (int iq=0;iq<16;iq++){
        f32x4 a = *(const f32x4*)&ss[iq][k4*4];
        #pragma unroll
        for (int kk=0;kk<4;kk++){
          acc0[iq] += a[kk]*wa[kk];
          acc1[iq] += a[kk]*wbv[kk];
        }
      }
    }
    float bb0 = b2f(b1[n0]), bb1 = b2f(b1[n0+1]);
    #pragma unroll
    for (int iq=0;iq<16;iq++){
      float v0 = acc0[iq]+bb0, v1 = acc1[iq]+bb1;
      hs[iq][n0]   = v0 > 0.f ? v0 : 0.f;
      hs[iq][n0+1] = v1 > 0.f ? v1 : 0.f;
    }
  }
  __syncthreads();
  // phase 2: out = hs @ w2 + b2 + ss, LN
  const int tn = tid & 31, tm = tid >> 5;   // 4 cols, 2 q per thread
  float acc[2][4];
  #pragma unroll
  for (int iq=0;iq<2;iq++)
    #pragma unroll
    for (int j=0;j<4;j++) acc[iq][j]=0.f;
  for (int k4 = 0; k4 < 128; k4++){
    float w[4][4];
    #pragma unroll
    for (int kk=0;kk<4;kk++){
      u16x4 wu = *(const u16x4*)&w2[(size_t)(k4*4+kk)*128 + tn*4];
      #pragma unroll
      for (int j=0;j<4;j++) w[kk][j] = b2f(wu[j]);
    }
    #pragma unroll
    for (int iq=0;iq<2;iq++){
      f32x4 a = *(const f32x4*)&hs[tm*2+iq][k4*4];
      #pragma unroll
      for (int kk=0;kk<4;kk++)
        #pragma unroll
        for (int j=0;j<4;j++)
          acc[iq][j] += a[kk]*w[kk][j];
    }
  }
  f32x4 g4, b4, bias4;
  #pragma unroll
  for (int j=0;j<4;j++){ g4[j]=b2f(gs[tn*4+j]); b4[j]=b2f(gb[tn*4+j]); bias4[j]=b2f(b2[tn*4+j]); }
  #pragma unroll
  for (int iq=0;iq<2;iq++){
    int ql = tm*2+iq;
    f32x4 r = *(const f32x4*)&ss[ql][tn*4];
    #pragma unroll
    for (int j=0;j<4;j++) r[j] += acc[iq][j] + bias4[j];
    float s1 = r[0]+r[1]+r[2]+r[3];
    float s2 = r[0]*r[0]+r[1]*r[1]+r[2]*r[2]+r[3]*r[3];
    #pragma unroll
    for (int off=16; off>0; off>>=1){
      s1 += __shfl_xor(s1, off, 64);
      s2 += __shfl_xor(s2, off, 64);
    }
    float mean = s1*(1.f/128.f);
    float var = s2*(1.f/128.f) - mean*mean;
    float inv = rsqrtf(var + 1e-5f);
    f32x4 outv;
    #pragma unroll
    for (int j=0;j<4;j++) outv[j] = (r[j]-mean)*inv*g4[j] + b4[j];
    *(f32x4*)&src[(size_t)(q0+ql)*128 + tn*4] = outv;
  }
}

// ---------------- outc: relu(src @ outc_w^T + b) -> fp32 [D][Q] ----------------
__global__ __launch_bounds__(256) void outc_kernel(const float* __restrict__ src,
    const ushort_t* __restrict__ cw, const ushort_t* __restrict__ cb,
    float* __restrict__ outp){
  __shared__ float as[64*128];       // 32KB
  __shared__ ushort_t wsb[128*128];  // 32KB: wsb[k][d] = cw[d][k]
  const int tid = threadIdx.x;
  const int q0 = blockIdx.x * 64;
  {
    int d = tid >> 1, c0 = (tid & 1) << 6;
    #pragma unroll
    for (int i8 = 0; i8 < 64; i8 += 8){
      u16x8 v = *(const u16x8*)&cw[d*128 + c0 + i8];
      #pragma unroll
      for (int i=0;i<8;i++) wsb[(c0+i8+i)*128 + d] = v[i];
    }
  }
  for (int i = tid*4; i < 64*128; i += 1024)
    *(f32x4*)&as[i] = *(const f32x4*)&src[(size_t)q0*128 + i];
  __syncthreads();
  const int tn = tid & 31, tm = tid >> 5;
  float acc[8][4];
  #pragma unroll
  for (int iq=0;iq<8;iq++)
    #pragma unroll
    for (int j=0;j<4;j++) acc[iq][j]=0.f;
  for (int k4 = 0; k4 < 32; k4++){
    float w[4][4];
    #pragma unroll
    for (int kk=0;kk<4;kk++){
      u16x4 wu = *(const u16x4*)&wsb[(k4*4+kk)*128 + tn*4];
      #pragma unroll
      for (int j=0;j<4;j++) w[kk][j] = b2f(wu[j]);
    }
    #pragma unroll
    for (int iq=0;iq<8;iq++){
      f32x4 a = *(const f32x4*)&as[(tm*8+iq)*128 + k4*4];
      #pragma unroll
      for (int kk=0;kk<4;kk++)
        #pragma unroll
        for (int j=0;j<4;j++)
          acc[iq][j] += a[kk]*w[kk][j];
    }
  }
  f32x4 bb;
  #pragma unroll
  for (int j=0;j<4;j++) bb[j] = b2f(cb[tn*4+j]);
  // direct scatter store (fp32 output, [D][Q] layout); epilogue-only cost
  #pragma unroll
  for (int iq=0;iq<8;iq++)
    #pragma unroll
    for (int j=0;j<4;j++){
      float v = acc[iq][j] + bb[j];
      v = v > 0.f ? v : 0.f;
      outp[(size_t)(tn*4+j)*Q_TOT + q0 + tm*8 + iq] = v;
    }
}

extern "C" void kernel_launch(void* const* d_in, const int* in_sizes, int n_in,
                              void* d_out, int out_size, void* d_ws, size_t ws_size,
                              hipStream_t stream){
  const float* x = (const float*)d_in[0];

  float* pos = (float*)d_ws;
  float* src = pos + (size_t)Q_TOT*128;
  float* val = src + (size_t)Q_TOT*128;
  float* loc = val + (size_t)Q_TOT*128;
  float* aw  = loc + (size_t)Q_TOT*64;
  float* o   = aw  + (size_t)Q_TOT*32;
  ushort_t* wbf = (ushort_t*)(o + (size_t)Q_TOT*128);

  // bf16 weight copies at fixed offsets inside wbf (all 16-elem aligned)
  const ushort_t* mw     = wbf + 0;
  const ushort_t* mb     = wbf + 65536;
  const ushort_t* off_w  = wbf + 65664;
  const ushort_t* off_b  = wbf + 90240;
  const ushort_t* aw_w   = wbf + 90432;
  const ushort_t* aw_b   = wbf + 102720;
  const ushort_t* val_w  = wbf + 102816;
  const ushort_t* val_b  = wbf + 151968;
  const ushort_t* out_w  = wbf + 152352;
  const ushort_t* out_b  = wbf + 201504;
  const ushort_t* n1_s   = wbf + 201888;
  const ushort_t* n1_b   = wbf + 202272;
  const ushort_t* l1_w   = wbf + 202656;
  const ushort_t* l1_b   = wbf + 399264;
  const ushort_t* l2_w   = wbf + 400800;
  const ushort_t* l2_b   = wbf + 597408;
  const ushort_t* n2_s   = wbf + 597792;
  const ushort_t* n2_b   = wbf + 598176;
  const ushort_t* outc_w = wbf + 598560;
  const ushort_t* outc_b = wbf + 614944;

  cvt_kernel<<<(CVT_TOT+255)/256, 256, 0, stream>>>(
      (const float*)d_in[1],  (const float*)d_in[2],  (const float*)d_in[3],
      (const float*)d_in[4],  (const float*)d_in[5],  (const float*)d_in[6],
      (const float*)d_in[7],  (const float*)d_in[8],  (const float*)d_in[9],
      (const float*)d_in[10], (const float*)d_in[11], (const float*)d_in[12],
      (const float*)d_in[13], (const float*)d_in[14], (const float*)d_in[15],
      (const float*)d_in[16], (const float*)d_in[17], (const float*)d_in[18],
      (const float*)d_in[19], (const float*)d_in[20], wbf);

  pos_kernel<<<Q_TOT*128/256, 256, 0, stream>>>(pos);
  merge_kernel<<<Q_TOT/64, 256, 0, stream>>>(x, mw, mb, src);
  for (int l = 0; l < 3; l++){
    offaw_kernel<<<Q_TOT/64, 256, 0, stream>>>(src, pos,
        off_w + (size_t)l*128*64, off_b + (size_t)l*64,
        aw_w  + (size_t)l*128*32, aw_b  + (size_t)l*32, loc, aw);
    val_kernel<<<Q_TOT/64, 256, 0, stream>>>(src,
        val_w + (size_t)l*128*128, val_b + (size_t)l*128, val);
    sample_kernel<<<Q_TOT/2, 256, 0, stream>>>(val, loc, aw, o);
    outln_kernel<<<Q_TOT/64, 256, 0, stream>>>(o,
        out_w + (size_t)l*128*128, out_b + (size_t)l*128,
        n1_s + (size_t)l*128, n1_b + (size_t)l*128, src);
    ffn_kernel<<<Q_TOT/16, 256, 0, stream>>>(
        l1_w + (size_t)l*128*512, l1_b + (size_t)l*512,
        l2_w + (size_t)l*512*128, l2_b + (size_t)l*128,
        n2_s + (size_t)l*128, n2_b + (size_t)l*128, src);
  }
  outc_kernel<<<Q_TOT/64, 256, 0, stream>>>(src, outc_w, outc_b, (float*)d_out);
}

// Round 3
// 869.537 us; speedup vs baseline: 1.5310x; 1.5310x over previous
//
#include <hip/hip_runtime.h>
#include <hip/hip_bf16.h>
#include <math.h>

#define Q_TOT 43200
#define H_ 120
#define W_ 360

typedef unsigned short ushort_t;
typedef float f32x4 __attribute__((ext_vector_type(4)));
typedef unsigned short u16x4 __attribute__((ext_vector_type(4)));
typedef unsigned short u16x8 __attribute__((ext_vector_type(8)));
using short8 = __attribute__((ext_vector_type(8))) short;

static __device__ __forceinline__ float b2f(unsigned short u){
  return __uint_as_float(((unsigned)u) << 16);
}
static __device__ __forceinline__ unsigned short f2b(float f){
  unsigned u = __float_as_uint(f);
  unsigned r = (u + 0x7fffu + ((u >> 16) & 1u)) >> 16;  // RNE
  return (unsigned short)r;
}

// swizzle: XOR byte-addr bits 4-6 with row&7 — kills the 16-way bank conflict
// on ds_read_b128 of row-major tiles (rows are 256B/512B strided)
#define SWZ(row, byte) ((byte) ^ (((row) & 7) << 4))

// ---------------- fp32 -> bf16 straight weight conversion ----------------
#define CVT_TOT 615072
__global__ __launch_bounds__(256) void cvt_kernel(
    const float* p0, const float* p1, const float* p2, const float* p3,
    const float* p4, const float* p5, const float* p6, const float* p7,
    const float* p8, const float* p9, const float* p10, const float* p11,
    const float* p12, const float* p13, const float* p14, const float* p15,
    const float* p16, const float* p17, const float* p18, const float* p19,
    ushort_t* __restrict__ dst){
  const float* ps[20] = {p0,p1,p2,p3,p4,p5,p6,p7,p8,p9,p10,p11,p12,p13,p14,p15,p16,p17,p18,p19};
  const int offs[20] = {0,65536,65664,90240,90432,102720,102816,151968,152352,201504,
                        201888,202272,202656,399264,400800,597408,597792,598176,598560,614944};
  int gid = blockIdx.x*256 + threadIdx.x;
  if (gid >= CVT_TOT) return;
  int s = 0;
  #pragma unroll
  for (int i=1;i<20;i++) s += (gid >= offs[i]) ? 1 : 0;
  dst[gid] = f2b(ps[s][gid - offs[s]]);
}

// ---------------- fp32 [L][K][N] -> bf16 transposed [L][N][K] ----------------
#define CVTT_TOT 491520
__global__ __launch_bounds__(256) void cvtT_kernel(
    const float* __restrict__ vw, const float* __restrict__ ow,
    const float* __restrict__ w1, const float* __restrict__ w2,
    ushort_t* __restrict__ dst){
  int gid = blockIdx.x*256 + threadIdx.x;
  if (gid >= CVTT_TOT) return;
  const float* s; int K, N, off;
  if (gid < 49152)      { s = vw; K = 128; N = 128; off = 0; }
  else if (gid < 98304) { s = ow; K = 128; N = 128; off = 49152; }
  else if (gid < 294912){ s = w1; K = 128; N = 512; off = 98304; }
  else                  { s = w2; K = 512; N = 128; off = 294912; }
  int e = gid - off;
  int per = K*N;
  int l = e / per, rem = e - l*per;
  int n = rem / K, k = rem - n*K;
  dst[gid] = f2b(s[(size_t)l*per + (size_t)k*N + n]);
}

// ---------------- pos embedding ----------------
__global__ __launch_bounds__(256) void pos_kernel(float* __restrict__ pos){
  int idx = blockIdx.x*256 + threadIdx.x;
  int q = idx >> 7, k = idx & 127;
  int qy = q / W_, qx = q - qy*W_;
  int kk = k & 63;
  float e;
  if (k < 64) e = (float)(qy+1) * (6.283185307179586f / ((float)H_ + 1e-6f));
  else        e = (float)(qx+1) * (6.283185307179586f / ((float)W_ + 1e-6f));
  int m = kk >> 1;
  float t = powf(10000.0f, (float)m * (1.0f/32.0f));
  float p = e / t;
  pos[idx] = (kk & 1) ? cosf(p) : sinf(p);
}

// ---------------- merge: src = relu(x^T @ merge_w^T + b), K=512, x fp32 ----------
__global__ __launch_bounds__(256) void merge_kernel(const float* __restrict__ x,
    const ushort_t* __restrict__ mw, const ushort_t* __restrict__ mb,
    float* __restrict__ src){
  __shared__ float xs[32][64];
  __shared__ float wls[32][128];
  const int tid = threadIdx.x;
  const int q0 = blockIdx.x * 64;
  const int tn = tid & 31, tm = tid >> 5;
  float acc[8][4];
  #pragma unroll
  for (int iq=0;iq<8;iq++)
    #pragma unroll
    for (int j=0;j<4;j++) acc[iq][j]=0.f;
  for (int k0 = 0; k0 < 512; k0 += 32){
    if (k0) __syncthreads();
    {
      int kk = tid >> 3, m0 = (tid & 7) << 3;
      const float* xp = x + (size_t)(k0+kk)*Q_TOT + q0 + m0;
      f32x4 v0 = *(const f32x4*)xp;
      f32x4 v1 = *(const f32x4*)(xp + 4);
      *(f32x4*)&xs[kk][m0]   = v0;
      *(f32x4*)&xs[kk][m0+4] = v1;
    }
    {
      int d = tid >> 1, h16 = (tid & 1) << 4;
      u16x8 v0 = *(const u16x8*)(mw + d*512 + k0 + h16);
      u16x8 v1 = *(const u16x8*)(mw + d*512 + k0 + h16 + 8);
      #pragma unroll
      for (int i=0;i<8;i++) wls[h16+i][d] = b2f(v0[i]);
      #pragma unroll
      for (int i=0;i<8;i++) wls[h16+8+i][d] = b2f(v1[i]);
    }
    __syncthreads();
    for (int kk = 0; kk < 32; kk++){
      f32x4 w = *(const f32x4*)&wls[kk][tn<<2];
      f32x4 a0 = *(const f32x4*)&xs[kk][tm<<3];
      f32x4 a1 = *(const f32x4*)&xs[kk][(tm<<3)+4];
      #pragma unroll
      for (int j=0;j<4;j++){
        acc[0][j] += a0[0]*w[j]; acc[1][j] += a0[1]*w[j];
        acc[2][j] += a0[2]*w[j]; acc[3][j] += a0[3]*w[j];
        acc[4][j] += a1[0]*w[j]; acc[5][j] += a1[1]*w[j];
        acc[6][j] += a1[2]*w[j]; acc[7][j] += a1[3]*w[j];
      }
    }
  }
  float bb[4];
  #pragma unroll
  for (int j=0;j<4;j++) bb[j] = b2f(mb[(tn<<2)+j]);
  #pragma unroll
  for (int iq=0;iq<8;iq++){
    f32x4 r;
    #pragma unroll
    for (int j=0;j<4;j++){ float v = acc[iq][j] + bb[j]; r[j] = v > 0.f ? v : 0.f; }
    *(f32x4*)&src[(size_t)(q0 + (tm<<3) + iq)*128 + (tn<<2)] = r;
  }
}

// ---------------- off/aw (vector, unchanged) ----------------
__global__ __launch_bounds__(256) void offaw_kernel(const float* __restrict__ src,
    const float* __restrict__ pos,
    const ushort_t* __restrict__ ow, const ushort_t* __restrict__ ob,
    const ushort_t* __restrict__ aww, const ushort_t* __restrict__ awb,
    float* __restrict__ loc, float* __restrict__ awg){
  __shared__ float qs[64*128];
  __shared__ ushort_t wb_s[128*96];
  const int tid = threadIdx.x;
  const int q0 = blockIdx.x * 64;
  for (int i = tid*4; i < 64*128; i += 1024){
    f32x4 s = *(const f32x4*)&src[(size_t)q0*128 + i];
    f32x4 p = *(const f32x4*)&pos[(size_t)q0*128 + i];
    *(f32x4*)&qs[i] = s + p;
  }
  for (int i = tid*8; i < 128*64; i += 2048){
    u16x8 v = *(const u16x8*)&ow[i];
    *(u16x8*)&wb_s[(i >> 6)*96 + (i & 63)] = v;
  }
  for (int i = tid*8; i < 128*32; i += 2048){
    u16x8 v = *(const u16x8*)&aww[i];
    *(u16x8*)&wb_s[(i >> 5)*96 + 64 + (i & 31)] = v;
  }
  __syncthreads();
  const int tn = tid & 31, tm = tid >> 5;
  float acc[8][3];
  #pragma unroll
  for (int iq=0;iq<8;iq++)
    #pragma unroll
    for (int j=0;j<3;j++) acc[iq][j]=0.f;
  for (int k4 = 0; k4 < 32; k4++){
    float w[4][3];
    #pragma unroll
    for (int kk=0;kk<4;kk++)
      #pragma unroll
      for (int j=0;j<3;j++)
        w[kk][j] = b2f(wb_s[(k4*4+kk)*96 + tn*3 + j]);
    #pragma unroll
    for (int iq=0;iq<8;iq++){
      f32x4 a = *(const f32x4*)&qs[(tm*8+iq)*128 + k4*4];
      #pragma unroll
      for (int kk=0;kk<4;kk++)
        #pragma unroll
        for (int j=0;j<3;j++)
          acc[iq][j] += a[kk]*w[kk][j];
    }
  }
  __syncthreads();
  #pragma unroll
  for (int iq=0;iq<8;iq++)
    #pragma unroll
    for (int j=0;j<3;j++)
      qs[(tm*8+iq)*96 + tn*3 + j] = acc[iq][j];
  __syncthreads();
  for (int u = tid; u < 512; u += 256){
    int qi = u >> 3, h = u & 7;
    int q = q0 + qi;
    const float* rw = &qs[qi*96];
    float av[4], mx = -1e30f;
    #pragma unroll
    for (int p=0;p<4;p++){ av[p] = rw[64 + h*4 + p] + b2f(awb[h*4+p]); mx = fmaxf(mx, av[p]); }
    float s = 0.f;
    #pragma unroll
    for (int p=0;p<4;p++){ av[p] = expf(av[p]-mx); s += av[p]; }
    float inv = 1.f/s;
    float qxf = (float)(q % W_);
    float qyf = (float)(q / W_);
    #pragma unroll
    for (int p=0;p<4;p++){
      awg[(size_t)q*32 + h*4 + p] = av[p]*inv;
      float ox = rw[h*8 + p*2]     + b2f(ob[h*8 + p*2]);
      float oy = rw[h*8 + p*2 + 1] + b2f(ob[h*8 + p*2 + 1]);
      loc[(size_t)q*64 + h*8 + p*2]     = qxf + ox;
      loc[(size_t)q*64 + h*8 + p*2 + 1] = qyf + oy;
    }
  }
}

// ================= MFMA helpers =================
// stage 64 rows x 128 cols of fp32 `a` into swizzled bf16 LDS tile
static __device__ __forceinline__ void stage_a(const float* __restrict__ a,
    ushort_t* a_lds, int tid){
  int row = tid >> 2, c0 = (tid & 3) * 32;
  const float* sp = a + (size_t)row*128 + c0;
  #pragma unroll
  for (int i=0;i<4;i++){
    f32x4 v0 = *(const f32x4*)(sp + i*8);
    f32x4 v1 = *(const f32x4*)(sp + i*8 + 4);
    u16x8 pk;
    pk[0]=f2b(v0[0]); pk[1]=f2b(v0[1]); pk[2]=f2b(v0[2]); pk[3]=f2b(v0[3]);
    pk[4]=f2b(v1[0]); pk[5]=f2b(v1[1]); pk[6]=f2b(v1[2]); pk[7]=f2b(v1[3]);
    int byte = row*256 + (c0 + i*8)*2;
    *(u16x8*)((char*)a_lds + SWZ(row, byte)) = pk;
  }
}

// ---------------- val = src @ val_w + b  (MFMA) ----------------
__global__ __launch_bounds__(256) void val_mfma(const float* __restrict__ A,
    const ushort_t* __restrict__ wt,   // [128 n][128 k] bf16 (transposed)
    const ushort_t* __restrict__ bias,
    float* __restrict__ outv){
  __shared__ ushort_t a_lds[64*128];
  const int tid = threadIdx.x;
  const int wave = tid >> 6, lane = tid & 63;
  const int lr = lane & 15, kg = lane >> 4;
  const int q0 = blockIdx.x * 64;
  stage_a(A + (size_t)q0*128, a_lds, tid);
  __syncthreads();
  const int qrow = wave*16 + lr;
  f32x4 acc[8];
  #pragma unroll
  for (int dt=0; dt<8; dt++) acc[dt] = (f32x4){0.f,0.f,0.f,0.f};
  #pragma unroll
  for (int dt=0; dt<8; dt++){
    const int drow = dt*16 + lr;
    #pragma unroll
    for (int ks=0; ks<4; ks++){
      short8 yf = *(const short8*)(wt + (size_t)drow*128 + ks*32 + kg*8);
      short8 xf = *(const short8*)((const char*)a_lds + SWZ(qrow, qrow*256 + (ks*32 + kg*8)*2));
      acc[dt] = __builtin_amdgcn_mfma_f32_16x16x32_bf16(xf, yf, acc[dt], 0, 0, 0);
    }
  }
  #pragma unroll
  for (int dt=0; dt<8; dt++){
    float bb = b2f(bias[dt*16 + lr]);
    #pragma unroll
    for (int r=0; r<4; r++){
      int q = q0 + wave*16 + kg*4 + r;
      outv[(size_t)q*128 + dt*16 + lr] = acc[dt][r] + bb;
    }
  }
}

// ---------------- out-proj + residual + LN (MFMA), in-place on srcio ----------
__global__ __launch_bounds__(256) void outln_mfma(const float* __restrict__ A,
    const ushort_t* __restrict__ wt,   // [128 n][128 k] bf16
    const ushort_t* __restrict__ bias,
    const ushort_t* __restrict__ gs, const ushort_t* __restrict__ gb,
    float* srcio){
  __shared__ ushort_t a_lds[64*128];
  const int tid = threadIdx.x;
  const int wave = tid >> 6, lane = tid & 63;
  const int lr = lane & 15, kg = lane >> 4;
  const int q0 = blockIdx.x * 64;
  stage_a(A + (size_t)q0*128, a_lds, tid);
  __syncthreads();
  const int qrow = wave*16 + lr;
  f32x4 acc[8];
  #pragma unroll
  for (int dt=0; dt<8; dt++) acc[dt] = (f32x4){0.f,0.f,0.f,0.f};
  #pragma unroll
  for (int dt=0; dt<8; dt++){
    const int drow = dt*16 + lr;
    #pragma unroll
    for (int ks=0; ks<4; ks++){
      short8 yf = *(const short8*)(wt + (size_t)drow*128 + ks*32 + kg*8);
      short8 xf = *(const short8*)((const char*)a_lds + SWZ(qrow, qrow*256 + (ks*32 + kg*8)*2));
      acc[dt] = __builtin_amdgcn_mfma_f32_16x16x32_bf16(xf, yf, acc[dt], 0, 0, 0);
    }
  }
  float g4[8], be4[8], bi4[8];
  #pragma unroll
  for (int dt=0; dt<8; dt++){
    g4[dt] = b2f(gs[dt*16+lr]); be4[dt] = b2f(gb[dt*16+lr]); bi4[dt] = b2f(bias[dt*16+lr]);
  }
  #pragma unroll
  for (int r=0; r<4; r++){
    const int q = q0 + wave*16 + kg*4 + r;
    float vals[8];
    float s1 = 0.f, s2 = 0.f;
    #pragma unroll
    for (int dt=0; dt<8; dt++){
      float v = acc[dt][r] + bi4[dt] + srcio[(size_t)q*128 + dt*16 + lr];
      vals[dt] = v; s1 += v; s2 += v*v;
    }
    #pragma unroll
    for (int m=1; m<16; m<<=1){ s1 += __shfl_xor(s1, m, 64); s2 += __shfl_xor(s2, m, 64); }
    float mean = s1*(1.f/128.f);
    float var  = s2*(1.f/128.f) - mean*mean;
    float inv  = rsqrtf(var + 1e-5f);
    #pragma unroll
    for (int dt=0; dt<8; dt++)
      srcio[(size_t)q*128 + dt*16 + lr] = (vals[dt]-mean)*inv*g4[dt] + be4[dt];
  }
}

// ---------------- fused FFN + residual + LN (MFMA), in-place on srcio ----------
__global__ __launch_bounds__(256) void ffn_mfma(
    const ushort_t* __restrict__ w1t,  // [512 n][128 k] bf16
    const ushort_t* __restrict__ b1,
    const ushort_t* __restrict__ w2t,  // [128 n][512 k] bf16
    const ushort_t* __restrict__ b2,
    const ushort_t* __restrict__ gs, const ushort_t* __restrict__ gb,
    float* srcio){
  __shared__ ushort_t a_lds[64*128];   // 16KB, swizzled, rows 256B
  __shared__ ushort_t h_lds[64*256];   // 32KB, swizzled, rows 512B (one N-half)
  const int tid = threadIdx.x;
  const int wave = tid >> 6, lane = tid & 63;
  const int lr = lane & 15, kg = lane >> 4;
  const int q0 = blockIdx.x * 64;
  stage_a(srcio + (size_t)q0*128, a_lds, tid);
  __syncthreads();
  f32x4 accd[8];
  #pragma unroll
  for (int dt=0; dt<8; dt++) accd[dt] = (f32x4){0.f,0.f,0.f,0.f};
  for (int half=0; half<2; half++){
    // GEMM1 (swapped): D[n][q] = W1t . src^T ; lane's 4 outputs are consecutive n
    for (int nt=0; nt<4; nt++){
      const int ngt = half*16 + wave*4 + nt;        // global 16-wide n-tile, 0..31
      const int nrow = ngt*16 + lr;                 // 0..511
      short8 xf[4];
      #pragma unroll
      for (int ks=0; ks<4; ks++)
        xf[ks] = *(const short8*)(w1t + (size_t)nrow*128 + ks*32 + kg*8);
      u16x4 bb = *(const u16x4*)(b1 + ngt*16 + kg*4);
      float bf[4];
      #pragma unroll
      for (int j=0;j<4;j++) bf[j] = b2f(bb[j]);
      #pragma unroll
      for (int qt=0; qt<4; qt++){
        f32x4 acc = (f32x4){0.f,0.f,0.f,0.f};
        const int q = qt*16 + lr;
        #pragma unroll
        for (int ks=0; ks<4; ks++){
          short8 yf = *(const short8*)((const char*)a_lds + SWZ(q, q*256 + (ks*32 + kg*8)*2));
          acc = __builtin_amdgcn_mfma_f32_16x16x32_bf16(xf[ks], yf, acc, 0, 0, 0);
        }
        const int nl = (ngt & 15)*16 + kg*4;        // local n within half, 0..255
        u16x4 hp;
        #pragma unroll
        for (int r=0;r<4;r++){ float v = acc[r] + bf[r]; hp[r] = f2b(v > 0.f ? v : 0.f); }
        *(u16x4*)((char*)h_lds + SWZ(q, q*512 + nl*2)) = hp;
      }
    }
    __syncthreads();
    // GEMM2 partial over this half's K-range
    const int qrow = wave*16 + lr;
    #pragma unroll
    for (int dt=0; dt<8; dt++){
      const int drow = dt*16 + lr;
      #pragma unroll
      for (int ks=0; ks<8; ks++){
        short8 yf = *(const short8*)(w2t + (size_t)drow*512 + half*256 + ks*32 + kg*8);
        short8 xf2 = *(const short8*)((const char*)h_lds + SWZ(qrow, qrow*512 + (ks*32 + kg*8)*2));
        accd[dt] = __builtin_amdgcn_mfma_f32_16x16x32_bf16(xf2, yf, accd[dt], 0, 0, 0);
      }
    }
    __syncthreads();
  }
  // epilogue: bias + residual + LN
  float g4[8], be4[8], bi4[8];
  #pragma unroll
  for (int dt=0; dt<8; dt++){
    g4[dt] = b2f(gs[dt*16+lr]); be4[dt] = b2f(gb[dt*16+lr]); bi4[dt] = b2f(b2[dt*16+lr]);
  }
  #pragma unroll
  for (int r=0; r<4; r++){
    const int q = q0 + wave*16 + kg*4 + r;
    float vals[8];
    float s1 = 0.f, s2 = 0.f;
    #pragma unroll
    for (int dt=0; dt<8; dt++){
      float v = accd[dt][r] + bi4[dt] + srcio[(size_t)q*128 + dt*16 + lr];
      vals[dt] = v; s1 += v; s2 += v*v;
    }
    #pragma unroll
    for (int m=1; m<16; m<<=1){ s1 += __shfl_xor(s1, m, 64); s2 += __shfl_xor(s2, m, 64); }
    float mean = s1*(1.f/128.f);
    float var  = s2*(1.f/128.f) - mean*mean;
    float inv  = rsqrtf(var + 1e-5f);
    #pragma unroll
    for (int dt=0; dt<8; dt++)
      srcio[(size_t)q*128 + dt*16 + lr] = (vals[dt]-mean)*inv*g4[dt] + be4[dt];
  }
}

// ---------------- deformable bilinear sampling (unchanged) ----------------
__global__ __launch_bounds__(256) void sample_kernel(const float* __restrict__ val,
    const float* __restrict__ loc, const float* __restrict__ awg,
    float* __restrict__ o){
  __shared__ float sl[2][64];
  __shared__ float sa[2][32];
  const int tid = threadIdx.x;
  const int q0 = blockIdx.x * 2;
  if (tid < 128){ sl[tid>>6][tid&63] = loc[(size_t)q0*64 + tid]; }
  else if (tid < 192){ int t = tid-128; sa[t>>5][t&31] = awg[(size_t)q0*32 + t]; }
  __syncthreads();
  const int ql = tid >> 7, c = tid & 127;
  const int h = c >> 4;
  float acc = 0.f;
  #pragma unroll
  for (int p=0;p<4;p++){
    float x = sl[ql][h*8 + p*2];
    float y = sl[ql][h*8 + p*2 + 1];
    float wgt = sa[ql][h*4 + p];
    float x0f = floorf(x), y0f = floorf(y);
    float wx = x - x0f, wy = y - y0f;
    int ix = (int)x0f, iy = (int)y0f;
    float s = 0.f;
    #pragma unroll
    for (int dy=0;dy<2;dy++){
      int yy = iy + dy;
      if (yy < 0 || yy >= H_) continue;
      float wyv = dy ? wy : 1.f - wy;
      #pragma unroll
      for (int dx=0;dx<2;dx++){
        int xx = ix + dx;
        if (xx < 0 || xx >= W_) continue;
        float wxv = dx ? wx : 1.f - wx;
        s += wyv*wxv*val[(size_t)(yy*W_ + xx)*128 + c];
      }
    }
    acc += wgt * s;
  }
  o[(size_t)(q0+ql)*128 + c] = acc;
}

// ---------------- outc (vector, unchanged): relu(src @ outc_w^T + b) -> [D][Q] ----
__global__ __launch_bounds__(256) void outc_kernel(const float* __restrict__ src,
    const ushort_t* __restrict__ cw, const ushort_t* __restrict__ cb,
    float* __restrict__ outp){
  __shared__ float as[64*128];
  __shared__ ushort_t wsb[128*128];
  const int tid = threadIdx.x;
  const int q0 = blockIdx.x * 64;
  {
    int d = tid >> 1, c0 = (tid & 1) << 6;
    #pragma unroll
    for (int i8 = 0; i8 < 64; i8 += 8){
      u16x8 v = *(const u16x8*)&cw[d*128 + c0 + i8];
      #pragma unroll
      for (int i=0;i<8;i++) wsb[(c0+i8+i)*128 + d] = v[i];
    }
  }
  for (int i = tid*4; i < 64*128; i += 1024)
    *(f32x4*)&as[i] = *(const f32x4*)&src[(size_t)q0*128 + i];
  __syncthreads();
  const int tn = tid & 31, tm = tid >> 5;
  float acc[8][4];
  #pragma unroll
  for (int iq=0;iq<8;iq++)
    #pragma unroll
    for (int j=0;j<4;j++) acc[iq][j]=0.f;
  for (int k4 = 0; k4 < 32; k4++){
    float w[4][4];
    #pragma unroll
    for (int kk=0;kk<4;kk++){
      u16x4 wu = *(const u16x4*)&wsb[(k4*4+kk)*128 + tn*4];
      #pragma unroll
      for (int j=0;j<4;j++) w[kk][j] = b2f(wu[j]);
    }
    #pragma unroll
    for (int iq=0;iq<8;iq++){
      f32x4 a = *(const f32x4*)&as[(tm*8+iq)*128 + k4*4];
      #pragma unroll
      for (int kk=0;kk<4;kk++)
        #pragma unroll
        for (int j=0;j<4;j++)
          acc[iq][j] += a[kk]*w[kk][j];
    }
  }
  f32x4 bb;
  #pragma unroll
  for (int j=0;j<4;j++) bb[j] = b2f(cb[tn*4+j]);
  #pragma unroll
  for (int iq=0;iq<8;iq++)
    #pragma unroll
    for (int j=0;j<4;j++){
      float v = acc[iq][j] + bb[j];
      v = v > 0.f ? v : 0.f;
      outp[(size_t)(tn*4+j)*Q_TOT + q0 + tm*8 + iq] = v;
    }
}

extern "C" void kernel_launch(void* const* d_in, const int* in_sizes, int n_in,
                              void* d_out, int out_size, void* d_ws, size_t ws_size,
                              hipStream_t stream){
  const float* x = (const float*)d_in[0];

  float* pos = (float*)d_ws;
  float* src = pos + (size_t)Q_TOT*128;
  float* val = src + (size_t)Q_TOT*128;
  float* loc = val + (size_t)Q_TOT*128;
  float* aw  = loc + (size_t)Q_TOT*64;
  float* o   = aw  + (size_t)Q_TOT*32;
  ushort_t* wbf = (ushort_t*)(o + (size_t)Q_TOT*128);

  // straight bf16 copies (same offsets as round 2)
  const ushort_t* mw     = wbf + 0;
  const ushort_t* mb     = wbf + 65536;
  const ushort_t* off_w  = wbf + 65664;
  const ushort_t* off_b  = wbf + 90240;
  const ushort_t* aw_w   = wbf + 90432;
  const ushort_t* aw_b   = wbf + 102720;
  const ushort_t* val_b  = wbf + 151968;
  const ushort_t* out_b  = wbf + 201504;
  const ushort_t* n1_s   = wbf + 201888;
  const ushort_t* n1_b   = wbf + 202272;
  const ushort_t* l1_b   = wbf + 399264;
  const ushort_t* l2_b   = wbf + 597408;
  const ushort_t* n2_s   = wbf + 597792;
  const ushort_t* n2_b   = wbf + 598176;
  const ushort_t* outc_w = wbf + 598560;
  const ushort_t* outc_b = wbf + 614944;
  // transposed bf16 [N][K]
  ushort_t* tbase = wbf + 615072;
  const ushort_t* val_wt = tbase + 0;       // 3 x [128][128]
  const ushort_t* out_wt = tbase + 49152;   // 3 x [128][128]
  const ushort_t* l1_wt  = tbase + 98304;   // 3 x [512][128]
  const ushort_t* l2_wt  = tbase + 294912;  // 3 x [128][512]

  cvt_kernel<<<(CVT_TOT+255)/256, 256, 0, stream>>>(
      (const float*)d_in[1],  (const float*)d_in[2],  (const float*)d_in[3],
      (const float*)d_in[4],  (const float*)d_in[5],  (const float*)d_in[6],
      (const float*)d_in[7],  (const float*)d_in[8],  (const float*)d_in[9],
      (const float*)d_in[10], (const float*)d_in[11], (const float*)d_in[12],
      (const float*)d_in[13], (const float*)d_in[14], (const float*)d_in[15],
      (const float*)d_in[16], (const float*)d_in[17], (const float*)d_in[18],
      (const float*)d_in[19], (const float*)d_in[20], wbf);
  cvtT_kernel<<<CVTT_TOT/256, 256, 0, stream>>>(
      (const float*)d_in[7], (const float*)d_in[9],
      (const float*)d_in[13], (const float*)d_in[15], tbase);

  pos_kernel<<<Q_TOT*128/256, 256, 0, stream>>>(pos);
  merge_kernel<<<Q_TOT/64, 256, 0, stream>>>(x, mw, mb, src);
  for (int l = 0; l < 3; l++){
    offaw_kernel<<<Q_TOT/64, 256, 0, stream>>>(src, pos,
        off_w + (size_t)l*128*64, off_b + (size_t)l*64,
        aw_w  + (size_t)l*128*32, aw_b  + (size_t)l*32, loc, aw);
    val_mfma<<<Q_TOT/64, 256, 0, stream>>>(src,
        val_wt + (size_t)l*128*128, val_b + (size_t)l*128, val);
    sample_kernel<<<Q_TOT/2, 256, 0, stream>>>(val, loc, aw, o);
    outln_mfma<<<Q_TOT/64, 256, 0, stream>>>(o,
        out_wt + (size_t)l*128*128, out_b + (size_t)l*128,
        n1_s + (size_t)l*128, n1_b + (size_t)l*128, src);
    ffn_mfma<<<Q_TOT/64, 256, 0, stream>>>(
        l1_wt + (size_t)l*512*128, l1_b + (size_t)l*512,
        l2_wt + (size_t)l*128*512, l2_b + (size_t)l*128,
        n2_s + (size_t)l*128, n2_b + (size_t)l*128, src);
  }
  outc_kernel<<<Q_TOT/64, 256, 0, stream>>>(src, outc_w, outc_b, (float*)d_out);
}

// Round 4
// 695.832 us; speedup vs baseline: 1.9132x; 1.2496x over previous
//
#include <hip/hip_runtime.h>
#include <hip/hip_bf16.h>
#include <math.h>

#define Q_TOT 43200
#define H_ 120
#define W_ 360

typedef unsigned short ushort_t;
typedef float f32x4 __attribute__((ext_vector_type(4)));
typedef unsigned short u16x4 __attribute__((ext_vector_type(4)));
typedef unsigned short u16x8 __attribute__((ext_vector_type(8)));
using short8 = __attribute__((ext_vector_type(8))) short;

static __device__ __forceinline__ float b2f(unsigned short u){
  return __uint_as_float(((unsigned)u) << 16);
}
static __device__ __forceinline__ unsigned short f2b(float f){
  unsigned u = __float_as_uint(f);
  unsigned r = (u + 0x7fffu + ((u >> 16) & 1u)) >> 16;  // RNE
  return (unsigned short)r;
}

// XOR-swizzle byte addr bits 4-6 with row&7 — kills bank conflicts on
// ds_read_b128 of row-major 256B/512B-strided tiles
#define SWZ(row, byte) ((byte) ^ (((row) & 7) << 4))

// ---------------- fp32 -> bf16 straight weight conversion ----------------
#define CVT_TOT 615072
__global__ __launch_bounds__(256) void cvt_kernel(
    const float* p0, const float* p1, const float* p2, const float* p3,
    const float* p4, const float* p5, const float* p6, const float* p7,
    const float* p8, const float* p9, const float* p10, const float* p11,
    const float* p12, const float* p13, const float* p14, const float* p15,
    const float* p16, const float* p17, const float* p18, const float* p19,
    ushort_t* __restrict__ dst){
  const float* ps[20] = {p0,p1,p2,p3,p4,p5,p6,p7,p8,p9,p10,p11,p12,p13,p14,p15,p16,p17,p18,p19};
  const int offs[20] = {0,65536,65664,90240,90432,102720,102816,151968,152352,201504,
                        201888,202272,202656,399264,400800,597408,597792,598176,598560,614944};
  int gid = blockIdx.x*256 + threadIdx.x;
  if (gid >= CVT_TOT) return;
  int s = 0;
  #pragma unroll
  for (int i=1;i<20;i++) s += (gid >= offs[i]) ? 1 : 0;
  dst[gid] = f2b(ps[s][gid - offs[s]]);
}

// ---- fp32 [L][K][N] -> bf16 [L][N][K]; last segment fuses off_w|aw_w into [96][128]
#define CVTT_TOT 528384
__global__ __launch_bounds__(256) void cvtT_kernel(
    const float* __restrict__ vw, const float* __restrict__ ow,
    const float* __restrict__ w1, const float* __restrict__ w2,
    const float* __restrict__ offw, const float* __restrict__ aww,
    ushort_t* __restrict__ dst){
  int gid = blockIdx.x*256 + threadIdx.x;
  if (gid >= CVTT_TOT) return;
  if (gid >= 491520){           // oaw_t: per layer [96 n][128 k]
    int e = gid - 491520;
    int l = e / 12288, rem = e - l*12288;
    int n = rem >> 7, k = rem & 127;
    float v = (n < 64) ? offw[((size_t)l*128 + k)*64 + n]
                       : aww [((size_t)l*128 + k)*32 + (n-64)];
    dst[gid] = f2b(v);
    return;
  }
  const float* s; int K, N, off;
  if (gid < 49152)      { s = vw; K = 128; N = 128; off = 0; }
  else if (gid < 98304) { s = ow; K = 128; N = 128; off = 49152; }
  else if (gid < 294912){ s = w1; K = 128; N = 512; off = 98304; }
  else                  { s = w2; K = 512; N = 128; off = 294912; }
  int e = gid - off;
  int per = K*N;
  int l = e / per, rem = e - l*per;
  int n = rem / K, k = rem - n*K;
  dst[gid] = f2b(s[(size_t)l*per + (size_t)k*N + n]);
}

// ---------------- separable pos tables: py[120][64] | px[360][64] ----------------
__global__ __launch_bounds__(256) void postab_kernel(float* __restrict__ tab){
  int gid = blockIdx.x*256 + threadIdx.x;
  if (gid >= 480*64) return;
  int row = gid >> 6, k = gid & 63;
  int m = k >> 1;
  float t = powf(10000.0f, (float)m * (1.0f/32.0f));
  float e;
  if (row < 120) e = (float)(row+1)   * (6.283185307179586f/((float)H_+1e-6f));
  else           e = (float)(row-119) * (6.283185307179586f/((float)W_+1e-6f));
  float p = e / t;
  tab[gid] = (k & 1) ? cosf(p) : sinf(p);
}

// ---------------- merge (MFMA): src = relu(x^T @ mw^T + b), K=512 ----------------
__global__ __launch_bounds__(256) void merge_mfma(const float* __restrict__ x,
    const ushort_t* __restrict__ mw,   // [128 d][512 c] bf16
    const ushort_t* __restrict__ mb,
    float* __restrict__ src){
  __shared__ ushort_t xt[64*128];      // 16KB swizzled [64 q][128 c]
  const int tid = threadIdx.x;
  const int wave = tid >> 6, lane = tid & 63;
  const int lr = lane & 15, kg = lane >> 4;
  const int q0 = blockIdx.x * 64;
  f32x4 acc[8];
  #pragma unroll
  for (int dt=0; dt<8; dt++) acc[dt] = (f32x4){0.f,0.f,0.f,0.f};
  for (int ch = 0; ch < 4; ch++){
    if (ch) __syncthreads();
    { // stage transpose: xt[q][c] = bf16(x[c_global][q0+q]); q=lane, c=wave*32+...
      const float* xp = x + (size_t)(ch*128 + wave*32)*Q_TOT + q0 + lane;
      #pragma unroll
      for (int jj0=0; jj0<8; jj0++){
        int jj = (jj0 + (lane>>3)) & 7;          // rotation: 8-way -> 4-way LDS conflict
        u16x4 pk;
        #pragma unroll
        for (int u=0;u<4;u++)
          pk[u] = f2b(xp[(size_t)(jj*4+u)*Q_TOT]);
        int byte = lane*256 + (wave*32 + jj*4)*2;
        *(u16x4*)((char*)xt + SWZ(lane, byte)) = pk;
      }
    }
    __syncthreads();
    const int qrow = wave*16 + lr;
    #pragma unroll
    for (int dt=0; dt<8; dt++){
      const int drow = dt*16 + lr;
      #pragma unroll
      for (int ks=0; ks<4; ks++){
        short8 wf = *(const short8*)(mw + (size_t)drow*512 + ch*128 + ks*32 + kg*8);
        short8 xf = *(const short8*)((const char*)xt + SWZ(qrow, qrow*256 + (ks*32 + kg*8)*2));
        acc[dt] = __builtin_amdgcn_mfma_f32_16x16x32_bf16(xf, wf, acc[dt], 0, 0, 0);
      }
    }
  }
  #pragma unroll
  for (int dt=0; dt<8; dt++){
    float bb = b2f(mb[dt*16 + lr]);
    #pragma unroll
    for (int r=0; r<4; r++){
      int q = q0 + wave*16 + kg*4 + r;
      float v = acc[dt][r] + bb;
      src[(size_t)q*128 + dt*16 + lr] = v > 0.f ? v : 0.f;
    }
  }
}

// ---------------- offaw (MFMA): [off|aw] = (src+pos) @ oaw_t^T, softmax, loc ------
__global__ __launch_bounds__(256) void offaw_mfma(const float* __restrict__ src,
    const float* __restrict__ py, const float* __restrict__ px,
    const ushort_t* __restrict__ wt,   // [96 n][128 k] bf16
    const ushort_t* __restrict__ ob, const ushort_t* __restrict__ awb,
    float* __restrict__ loc, float* __restrict__ awg){
  __shared__ ushort_t qlds[64*128];    // 16KB swizzled
  const int tid = threadIdx.x;
  const int wave = tid >> 6, lane = tid & 63;
  const int lr = lane & 15, kg = lane >> 4;
  const int q0 = blockIdx.x * 64;
  { // stage q = src + pos(table)
    int row = tid >> 2, c0 = (tid & 3) * 32;
    int q = q0 + row, qy = q / W_, qx = q - qy*W_;
    const float* sp = src + (size_t)q*128 + c0;
    const float* tp = (c0 < 64) ? (py + qy*64 + c0) : (px + qx*64 + (c0 - 64));
    #pragma unroll
    for (int i=0;i<4;i++){
      f32x4 s0 = *(const f32x4*)(sp + i*8), s1 = *(const f32x4*)(sp + i*8 + 4);
      f32x4 t0 = *(const f32x4*)(tp + i*8), t1 = *(const f32x4*)(tp + i*8 + 4);
      u16x8 pk;
      #pragma unroll
      for (int j=0;j<4;j++){ pk[j] = f2b(s0[j]+t0[j]); pk[4+j] = f2b(s1[j]+t1[j]); }
      int byte = row*256 + (c0 + i*8)*2;
      *(u16x8*)((char*)qlds + SWZ(row, byte)) = pk;
    }
  }
  __syncthreads();
  const int qrow = wave*16 + lr;
  f32x4 acc[6];
  #pragma unroll
  for (int dt=0; dt<6; dt++) acc[dt] = (f32x4){0.f,0.f,0.f,0.f};
  #pragma unroll
  for (int dt=0; dt<6; dt++){
    const int nrow = dt*16 + lr;
    #pragma unroll
    for (int ks=0; ks<4; ks++){
      short8 wf = *(const short8*)(wt + (size_t)nrow*128 + ks*32 + kg*8);
      short8 xf = *(const short8*)((const char*)qlds + SWZ(qrow, qrow*256 + (ks*32 + kg*8)*2));
      acc[dt] = __builtin_amdgcn_mfma_f32_16x16x32_bf16(xf, wf, acc[dt], 0, 0, 0);
    }
  }
  #pragma unroll
  for (int r=0; r<4; r++){
    int q = q0 + wave*16 + kg*4 + r;
    int qy = q / W_, qx = q - qy*W_;
    float qxf = (float)qx, qyf = (float)qy;
    // loc: n = h*8 + p*2 + {0:x,1:y};  x = qx + off_x (the 0.5s cancel)
    #pragma unroll
    for (int dt=0; dt<4; dt++){
      int n = dt*16 + lr;
      float v = acc[dt][r] + b2f(ob[n]);
      loc[(size_t)q*64 + n] = ((n & 1) ? qyf : qxf) + v;
    }
    // aw: softmax over p = idx&3 — 4-lane group reduce
    #pragma unroll
    for (int d4=0; d4<2; d4++){
      int idx = d4*16 + lr;
      float v = acc[4+d4][r] + b2f(awb[idx]);
      float mx = fmaxf(v, __shfl_xor(v, 1, 64));
      mx = fmaxf(mx, __shfl_xor(mx, 2, 64));
      float e = expf(v - mx);
      float s = e + __shfl_xor(e, 1, 64);
      s = s + __shfl_xor(s, 2, 64);
      awg[(size_t)q*32 + idx] = e / s;
    }
  }
}

// ---------------- val = src @ val_w + b (MFMA) -> bf16 ----------------
__global__ __launch_bounds__(256) void val_mfma(const float* __restrict__ A,
    const ushort_t* __restrict__ wt,   // [128 n][128 k] bf16
    const ushort_t* __restrict__ bias,
    ushort_t* __restrict__ outv){
  __shared__ ushort_t a_lds[64*128];
  const int tid = threadIdx.x;
  const int wave = tid >> 6, lane = tid & 63;
  const int lr = lane & 15, kg = lane >> 4;
  const int q0 = blockIdx.x * 64;
  { // stage fp32 src -> swizzled bf16
    int row = tid >> 2, c0 = (tid & 3) * 32;
    const float* sp = A + (size_t)(q0+row)*128 + c0;
    #pragma unroll
    for (int i=0;i<4;i++){
      f32x4 v0 = *(const f32x4*)(sp + i*8);
      f32x4 v1 = *(const f32x4*)(sp + i*8 + 4);
      u16x8 pk;
      #pragma unroll
      for (int j=0;j<4;j++){ pk[j]=f2b(v0[j]); pk[4+j]=f2b(v1[j]); }
      int byte = row*256 + (c0 + i*8)*2;
      *(u16x8*)((char*)a_lds + SWZ(row, byte)) = pk;
    }
  }
  __syncthreads();
  const int qrow = wave*16 + lr;
  f32x4 acc[8];
  #pragma unroll
  for (int dt=0; dt<8; dt++) acc[dt] = (f32x4){0.f,0.f,0.f,0.f};
  #pragma unroll
  for (int dt=0; dt<8; dt++){
    const int drow = dt*16 + lr;
    #pragma unroll
    for (int ks=0; ks<4; ks++){
      short8 yf = *(const short8*)(wt + (size_t)drow*128 + ks*32 + kg*8);
      short8 xf = *(const short8*)((const char*)a_lds + SWZ(qrow, qrow*256 + (ks*32 + kg*8)*2));
      acc[dt] = __builtin_amdgcn_mfma_f32_16x16x32_bf16(xf, yf, acc[dt], 0, 0, 0);
    }
  }
  #pragma unroll
  for (int dt=0; dt<8; dt++){
    float bb = b2f(bias[dt*16 + lr]);
    #pragma unroll
    for (int r=0; r<4; r++){
      int q = q0 + wave*16 + kg*4 + r;
      outv[(size_t)q*128 + dt*16 + lr] = f2b(acc[dt][r] + bb);
    }
  }
}

// ---------------- out-proj + residual + LN (MFMA), in-place on srcio ----------
__global__ __launch_bounds__(256) void outln_mfma(const float* __restrict__ A,
    const ushort_t* __restrict__ wt,   // [128 n][128 k] bf16
    const ushort_t* __restrict__ bias,
    const ushort_t* __restrict__ gs, const ushort_t* __restrict__ gb,
    float* srcio){
  __shared__ ushort_t a_lds[64*128];
  const int tid = threadIdx.x;
  const int wave = tid >> 6, lane = tid & 63;
  const int lr = lane & 15, kg = lane >> 4;
  const int q0 = blockIdx.x * 64;
  {
    int row = tid >> 2, c0 = (tid & 3) * 32;
    const float* sp = A + (size_t)(q0+row)*128 + c0;
    #pragma unroll
    for (int i=0;i<4;i++){
      f32x4 v0 = *(const f32x4*)(sp + i*8);
      f32x4 v1 = *(const f32x4*)(sp + i*8 + 4);
      u16x8 pk;
      #pragma unroll
      for (int j=0;j<4;j++){ pk[j]=f2b(v0[j]); pk[4+j]=f2b(v1[j]); }
      int byte = row*256 + (c0 + i*8)*2;
      *(u16x8*)((char*)a_lds + SWZ(row, byte)) = pk;
    }
  }
  __syncthreads();
  const int qrow = wave*16 + lr;
  f32x4 acc[8];
  #pragma unroll
  for (int dt=0; dt<8; dt++) acc[dt] = (f32x4){0.f,0.f,0.f,0.f};
  #pragma unroll
  for (int dt=0; dt<8; dt++){
    const int drow = dt*16 + lr;
    #pragma unroll
    for (int ks=0; ks<4; ks++){
      short8 yf = *(const short8*)(wt + (size_t)drow*128 + ks*32 + kg*8);
      short8 xf = *(const short8*)((const char*)a_lds + SWZ(qrow, qrow*256 + (ks*32 + kg*8)*2));
      acc[dt] = __builtin_amdgcn_mfma_f32_16x16x32_bf16(xf, yf, acc[dt], 0, 0, 0);
    }
  }
  float g4[8], be4[8], bi4[8];
  #pragma unroll
  for (int dt=0; dt<8; dt++){
    g4[dt] = b2f(gs[dt*16+lr]); be4[dt] = b2f(gb[dt*16+lr]); bi4[dt] = b2f(bias[dt*16+lr]);
  }
  #pragma unroll
  for (int r=0; r<4; r++){
    const int q = q0 + wave*16 + kg*4 + r;
    float vals[8];
    float s1 = 0.f, s2 = 0.f;
    #pragma unroll
    for (int dt=0; dt<8; dt++){
      float v = acc[dt][r] + bi4[dt] + srcio[(size_t)q*128 + dt*16 + lr];
      vals[dt] = v; s1 += v; s2 += v*v;
    }
    #pragma unroll
    for (int m=1; m<16; m<<=1){ s1 += __shfl_xor(s1, m, 64); s2 += __shfl_xor(s2, m, 64); }
    float mean = s1*(1.f/128.f);
    float var  = s2*(1.f/128.f) - mean*mean;
    float inv  = rsqrtf(var + 1e-5f);
    #pragma unroll
    for (int dt=0; dt<8; dt++)
      srcio[(size_t)q*128 + dt*16 + lr] = (vals[dt]-mean)*inv*g4[dt] + be4[dt];
  }
}

// ---------------- fused FFN + residual + LN (MFMA), in-place on srcio ----------
__global__ __launch_bounds__(256) void ffn_mfma(
    const ushort_t* __restrict__ w1t,  // [512 n][128 k] bf16
    const ushort_t* __restrict__ b1,
    const ushort_t* __restrict__ w2t,  // [128 n][512 k] bf16
    const ushort_t* __restrict__ b2,
    const ushort_t* __restrict__ gs, const ushort_t* __restrict__ gb,
    float* srcio){
  __shared__ ushort_t a_lds[64*128];   // 16KB swizzled, rows 256B
  __shared__ ushort_t h_lds[64*256];   // 32KB swizzled, rows 512B (one N-half)
  const int tid = threadIdx.x;
  const int wave = tid >> 6, lane = tid & 63;
  const int lr = lane & 15, kg = lane >> 4;
  const int q0 = blockIdx.x * 64;
  {
    int row = tid >> 2, c0 = (tid & 3) * 32;
    const float* sp = srcio + (size_t)(q0+row)*128 + c0;
    #pragma unroll
    for (int i=0;i<4;i++){
      f32x4 v0 = *(const f32x4*)(sp + i*8);
      f32x4 v1 = *(const f32x4*)(sp + i*8 + 4);
      u16x8 pk;
      #pragma unroll
      for (int j=0;j<4;j++){ pk[j]=f2b(v0[j]); pk[4+j]=f2b(v1[j]); }
      int byte = row*256 + (c0 + i*8)*2;
      *(u16x8*)((char*)a_lds + SWZ(row, byte)) = pk;
    }
  }
  __syncthreads();
  f32x4 accd[8];
  #pragma unroll
  for (int dt=0; dt<8; dt++) accd[dt] = (f32x4){0.f,0.f,0.f,0.f};
  for (int half=0; half<2; half++){
    // GEMM1 swapped: D[n][q]; lane's 4 outputs = consecutive n -> direct [q][n] LDS write
    for (int nt=0; nt<4; nt++){
      const int ngt = half*16 + wave*4 + nt;
      const int nrow = ngt*16 + lr;
      short8 xf[4];
      #pragma unroll
      for (int ks=0; ks<4; ks++)
        xf[ks] = *(const short8*)(w1t + (size_t)nrow*128 + ks*32 + kg*8);
      u16x4 bb = *(const u16x4*)(b1 + ngt*16 + kg*4);
      float bf[4];
      #pragma unroll
      for (int j=0;j<4;j++) bf[j] = b2f(bb[j]);
      #pragma unroll
      for (int qt=0; qt<4; qt++){
        f32x4 acc = (f32x4){0.f,0.f,0.f,0.f};
        const int q = qt*16 + lr;
        #pragma unroll
        for (int ks=0; ks<4; ks++){
          short8 yf = *(const short8*)((const char*)a_lds + SWZ(q, q*256 + (ks*32 + kg*8)*2));
          acc = __builtin_amdgcn_mfma_f32_16x16x32_bf16(xf[ks], yf, acc, 0, 0, 0);
        }
        const int nl = (ngt & 15)*16 + kg*4;
        u16x4 hp;
        #pragma unroll
        for (int r=0;r<4;r++){ float v = acc[r] + bf[r]; hp[r] = f2b(v > 0.f ? v : 0.f); }
        *(u16x4*)((char*)h_lds + SWZ(q, q*512 + nl*2)) = hp;
      }
    }
    __syncthreads();
    const int qrow = wave*16 + lr;
    #pragma unroll
    for (int dt=0; dt<8; dt++){
      const int drow = dt*16 + lr;
      #pragma unroll
      for (int ks=0; ks<8; ks++){
        short8 yf = *(const short8*)(w2t + (size_t)drow*512 + half*256 + ks*32 + kg*8);
        short8 xf2 = *(const short8*)((const char*)h_lds + SWZ(qrow, qrow*512 + (ks*32 + kg*8)*2));
        accd[dt] = __builtin_amdgcn_mfma_f32_16x16x32_bf16(xf2, yf, accd[dt], 0, 0, 0);
      }
    }
    __syncthreads();
  }
  float g4[8], be4[8], bi4[8];
  #pragma unroll
  for (int dt=0; dt<8; dt++){
    g4[dt] = b2f(gs[dt*16+lr]); be4[dt] = b2f(gb[dt*16+lr]); bi4[dt] = b2f(b2[dt*16+lr]);
  }
  #pragma unroll
  for (int r=0; r<4; r++){
    const int q = q0 + wave*16 + kg*4 + r;
    float vals[8];
    float s1 = 0.f, s2 = 0.f;
    #pragma unroll
    for (int dt=0; dt<8; dt++){
      float v = accd[dt][r] + bi4[dt] + srcio[(size_t)q*128 + dt*16 + lr];
      vals[dt] = v; s1 += v; s2 += v*v;
    }
    #pragma unroll
    for (int m=1; m<16; m<<=1){ s1 += __shfl_xor(s1, m, 64); s2 += __shfl_xor(s2, m, 64); }
    float mean = s1*(1.f/128.f);
    float var  = s2*(1.f/128.f) - mean*mean;
    float inv  = rsqrtf(var + 1e-5f);
    #pragma unroll
    for (int dt=0; dt<8; dt++)
      srcio[(size_t)q*128 + dt*16 + lr] = (vals[dt]-mean)*inv*g4[dt] + be4[dt];
  }
}

// ---------------- deformable bilinear sampling (bf16 val) ----------------
__global__ __launch_bounds__(256) void sample_kernel(const ushort_t* __restrict__ val,
    const float* __restrict__ loc, const float* __restrict__ awg,
    float* __restrict__ o){
  __shared__ float sl[2][64];
  __shared__ float sa[2][32];
  const int tid = threadIdx.x;
  const int q0 = blockIdx.x * 2;
  if (tid < 128){ sl[tid>>6][tid&63] = loc[(size_t)q0*64 + tid]; }
  else if (tid < 192){ int t = tid-128; sa[t>>5][t&31] = awg[(size_t)q0*32 + t]; }
  __syncthreads();
  const int ql = tid >> 7, c = tid & 127;
  const int h = c >> 4;
  float acc = 0.f;
  #pragma unroll
  for (int p=0;p<4;p++){
    float x = sl[ql][h*8 + p*2];
    float y = sl[ql][h*8 + p*2 + 1];
    float wgt = sa[ql][h*4 + p];
    float x0f = floorf(x), y0f = floorf(y);
    float wx = x - x0f, wy = y - y0f;
    int ix = (int)x0f, iy = (int)y0f;
    float s = 0.f;
    #pragma unroll
    for (int dy=0;dy<2;dy++){
      int yy = iy + dy;
      if (yy < 0 || yy >= H_) continue;
      float wyv = dy ? wy : 1.f - wy;
      #pragma unroll
      for (int dx=0;dx<2;dx++){
        int xx = ix + dx;
        if (xx < 0 || xx >= W_) continue;
        float wxv = dx ? wx : 1.f - wx;
        s += wyv*wxv*b2f(val[(size_t)(yy*W_ + xx)*128 + c]);
      }
    }
    acc += wgt * s;
  }
  o[(size_t)(q0+ql)*128 + c] = acc;
}

// ---------------- outc (vector): relu(src @ outc_w^T + b) -> fp32 [D][Q] ----
__global__ __launch_bounds__(256) void outc_kernel(const float* __restrict__ src,
    const ushort_t* __restrict__ cw, const ushort_t* __restrict__ cb,
    float* __restrict__ outp){
  __shared__ float as[64*128];
  __shared__ ushort_t wsb[128*128];
  const int tid = threadIdx.x;
  const int q0 = blockIdx.x * 64;
  {
    int d = tid >> 1, c0 = (tid & 1) << 6;
    #pragma unroll
    for (int i8 = 0; i8 < 64; i8 += 8){
      u16x8 v = *(const u16x8*)&cw[d*128 + c0 + i8];
      #pragma unroll
      for (int i=0;i<8;i++) wsb[(c0+i8+i)*128 + d] = v[i];
    }
  }
  for (int i = tid*4; i < 64*128; i += 1024)
    *(f32x4*)&as[i] = *(const f32x4*)&src[(size_t)q0*128 + i];
  __syncthreads();
  const int tn = tid & 31, tm = tid >> 5;
  float acc[8][4];
  #pragma unroll
  for (int iq=0;iq<8;iq++)
    #pragma unroll
    for (int j=0;j<4;j++) acc[iq][j]=0.f;
  for (int k4 = 0; k4 < 32; k4++){
    float w[4][4];
    #pragma unroll
    for (int kk=0;kk<4;kk++){
      u16x4 wu = *(const u16x4*)&wsb[(k4*4+kk)*128 + tn*4];
      #pragma unroll
      for (int j=0;j<4;j++) w[kk][j] = b2f(wu[j]);
    }
    #pragma unroll
    for (int iq=0;iq<8;iq++){
      f32x4 a = *(const f32x4*)&as[(tm*8+iq)*128 + k4*4];
      #pragma unroll
      for (int kk=0;kk<4;kk++)
        #pragma unroll
        for (int j=0;j<4;j++)
          acc[iq][j] += a[kk]*w[kk][j];
    }
  }
  f32x4 bb;
  #pragma unroll
  for (int j=0;j<4;j++) bb[j] = b2f(cb[tn*4+j]);
  #pragma unroll
  for (int iq=0;iq<8;iq++)
    #pragma unroll
    for (int j=0;j<4;j++){
      float v = acc[iq][j] + bb[j];
      v = v > 0.f ? v : 0.f;
      outp[(size_t)(tn*4+j)*Q_TOT + q0 + tm*8 + iq] = v;
    }
}

extern "C" void kernel_launch(void* const* d_in, const int* in_sizes, int n_in,
                              void* d_out, int out_size, void* d_ws, size_t ws_size,
                              hipStream_t stream){
  const float* x = (const float*)d_in[0];

  float* src = (float*)d_ws;
  float* loc = src + (size_t)Q_TOT*128;
  float* aw  = loc + (size_t)Q_TOT*64;
  float* o   = aw  + (size_t)Q_TOT*32;
  ushort_t* valbf = (ushort_t*)(o + (size_t)Q_TOT*128);
  ushort_t* wbf   = valbf + (size_t)Q_TOT*128;
  ushort_t* tbase = wbf + 615072;
  float* postab = (float*)(tbase + 528384);
  float* pytab = postab;
  float* pxtab = postab + 120*64;

  // straight bf16 copies
  const ushort_t* mw     = wbf + 0;
  const ushort_t* mb     = wbf + 65536;
  const ushort_t* off_b  = wbf + 90240;
  const ushort_t* aw_b   = wbf + 102720;
  const ushort_t* val_b  = wbf + 151968;
  const ushort_t* out_b  = wbf + 201504;
  const ushort_t* n1_s   = wbf + 201888;
  const ushort_t* n1_b   = wbf + 202272;
  const ushort_t* l1_b   = wbf + 399264;
  const ushort_t* l2_b   = wbf + 597408;
  const ushort_t* n2_s   = wbf + 597792;
  const ushort_t* n2_b   = wbf + 598176;
  const ushort_t* outc_w = wbf + 598560;
  const ushort_t* outc_b = wbf + 614944;
  // transposed bf16 [N][K]
  const ushort_t* val_wt = tbase + 0;       // 3 x [128][128]
  const ushort_t* out_wt = tbase + 49152;   // 3 x [128][128]
  const ushort_t* l1_wt  = tbase + 98304;   // 3 x [512][128]
  const ushort_t* l2_wt  = tbase + 294912;  // 3 x [128][512]
  const ushort_t* oaw_t  = tbase + 491520;  // 3 x [96][128]

  cvt_kernel<<<(CVT_TOT+255)/256, 256, 0, stream>>>(
      (const float*)d_in[1],  (const float*)d_in[2],  (const float*)d_in[3],
      (const float*)d_in[4],  (const float*)d_in[5],  (const float*)d_in[6],
      (const float*)d_in[7],  (const float*)d_in[8],  (const float*)d_in[9],
      (const float*)d_in[10], (const float*)d_in[11], (const float*)d_in[12],
      (const float*)d_in[13], (const float*)d_in[14], (const float*)d_in[15],
      (const float*)d_in[16], (const float*)d_in[17], (const float*)d_in[18],
      (const float*)d_in[19], (const float*)d_in[20], wbf);
  cvtT_kernel<<<CVTT_TOT/256, 256, 0, stream>>>(
      (const float*)d_in[7], (const float*)d_in[9],
      (const float*)d_in[13], (const float*)d_in[15],
      (const float*)d_in[3], (const float*)d_in[5], tbase);
  postab_kernel<<<120, 256, 0, stream>>>(postab);

  merge_mfma<<<Q_TOT/64, 256, 0, stream>>>(x, mw, mb, src);
  for (int l = 0; l < 3; l++){
    offaw_mfma<<<Q_TOT/64, 256, 0, stream>>>(src, pytab, pxtab,
        oaw_t + (size_t)l*96*128, off_b + (size_t)l*64, aw_b + (size_t)l*32,
        loc, aw);
    val_mfma<<<Q_TOT/64, 256, 0, stream>>>(src,
        val_wt + (size_t)l*128*128, val_b + (size_t)l*128, valbf);
    sample_kernel<<<Q_TOT/2, 256, 0, stream>>>(valbf, loc, aw, o);
    outln_mfma<<<Q_TOT/64, 256, 0, stream>>>(o,
        out_wt + (size_t)l*128*128, out_b + (size_t)l*128,
        n1_s + (size_t)l*128, n1_b + (size_t)l*128, src);
    ffn_mfma<<<Q_TOT/64, 256, 0, stream>>>(
        l1_wt + (size_t)l*512*128, l1_b + (size_t)l*512,
        l2_wt + (size_t)l*128*512, l2_b + (size_t)l*128,
        n2_s + (size_t)l*128, n2_b + (size_t)l*128, src);
  }
  outc_kernel<<<Q_TOT/64, 256, 0, stream>>>(src, outc_w, outc_b, (float*)d_out);
}

// Round 5
// 663.329 us; speedup vs baseline: 2.0070x; 1.0490x over previous
//
#include <hip/hip_runtime.h>
#include <hip/hip_bf16.h>
#include <math.h>

#define Q_TOT 43200
#define H_ 120
#define W_ 360

typedef unsigned short ushort_t;
typedef float f32x4 __attribute__((ext_vector_type(4)));
typedef unsigned short u16x4 __attribute__((ext_vector_type(4)));
typedef unsigned short u16x8 __attribute__((ext_vector_type(8)));
using short8 = __attribute__((ext_vector_type(8))) short;

static __device__ __forceinline__ float b2f(unsigned short u){
  return __uint_as_float(((unsigned)u) << 16);
}
static __device__ __forceinline__ unsigned short f2b(float f){
  unsigned u = __float_as_uint(f);
  unsigned r = (u + 0x7fffu + ((u >> 16) & 1u)) >> 16;  // RNE
  return (unsigned short)r;
}

// XOR-swizzle byte addr bits 4-6 with row&7 (stage rows consecutive in tid)
#define SWZ(row, byte) ((byte) ^ (((row) & 7) << 4))
// merge variant: rows within a staging write differ by 4, so fold in row>>3
// to keep both the b128 transpose-writes and the fragment reads 2-way
#define SWZ3(row, byte) ((byte) ^ ((((row) ^ ((row) >> 3)) & 7) << 4))

// ---------------- fp32 -> bf16 straight weight conversion ----------------
#define CVT_TOT 615072
__global__ __launch_bounds__(256) void cvt_kernel(
    const float* p0, const float* p1, const float* p2, const float* p3,
    const float* p4, const float* p5, const float* p6, const float* p7,
    const float* p8, const float* p9, const float* p10, const float* p11,
    const float* p12, const float* p13, const float* p14, const float* p15,
    const float* p16, const float* p17, const float* p18, const float* p19,
    ushort_t* __restrict__ dst){
  const float* ps[20] = {p0,p1,p2,p3,p4,p5,p6,p7,p8,p9,p10,p11,p12,p13,p14,p15,p16,p17,p18,p19};
  const int offs[20] = {0,65536,65664,90240,90432,102720,102816,151968,152352,201504,
                        201888,202272,202656,399264,400800,597408,597792,598176,598560,614944};
  int gid = blockIdx.x*256 + threadIdx.x;
  if (gid >= CVT_TOT) return;
  int s = 0;
  #pragma unroll
  for (int i=1;i<20;i++) s += (gid >= offs[i]) ? 1 : 0;
  dst[gid] = f2b(ps[s][gid - offs[s]]);
}

// ---- fp32 [L][K][N] -> bf16 [L][N][K]; last segment fuses off_w|aw_w into [96][128]
#define CVTT_TOT 528384
__global__ __launch_bounds__(256) void cvtT_kernel(
    const float* __restrict__ vw, const float* __restrict__ ow,
    const float* __restrict__ w1, const float* __restrict__ w2,
    const float* __restrict__ offw, const float* __restrict__ aww,
    ushort_t* __restrict__ dst){
  int gid = blockIdx.x*256 + threadIdx.x;
  if (gid >= CVTT_TOT) return;
  if (gid >= 491520){           // oaw_t: per layer [96 n][128 k]
    int e = gid - 491520;
    int l = e / 12288, rem = e - l*12288;
    int n = rem >> 7, k = rem & 127;
    float v = (n < 64) ? offw[((size_t)l*128 + k)*64 + n]
                       : aww [((size_t)l*128 + k)*32 + (n-64)];
    dst[gid] = f2b(v);
    return;
  }
  const float* s; int K, N, off;
  if (gid < 49152)      { s = vw; K = 128; N = 128; off = 0; }
  else if (gid < 98304) { s = ow; K = 128; N = 128; off = 49152; }
  else if (gid < 294912){ s = w1; K = 128; N = 512; off = 98304; }
  else                  { s = w2; K = 512; N = 128; off = 294912; }
  int e = gid - off;
  int per = K*N;
  int l = e / per, rem = e - l*per;
  int n = rem / K, k = rem - n*K;
  dst[gid] = f2b(s[(size_t)l*per + (size_t)k*N + n]);
}

// ---------------- separable pos tables: py[120][64] | px[360][64] ----------------
__global__ __launch_bounds__(256) void postab_kernel(float* __restrict__ tab){
  int gid = blockIdx.x*256 + threadIdx.x;
  if (gid >= 480*64) return;
  int row = gid >> 6, k = gid & 63;
  int m = k >> 1;
  float t = powf(10000.0f, (float)m * (1.0f/32.0f));
  float e;
  if (row < 120) e = (float)(row+1)   * (6.283185307179586f/((float)H_+1e-6f));
  else           e = (float)(row-119) * (6.283185307179586f/((float)W_+1e-6f));
  float p = e / t;
  tab[gid] = (k & 1) ? cosf(p) : sinf(p);
}

// ---------------- merge v2 (MFMA + dbuf + prefetch): src = relu(x^T@mw^T+b) ------
__global__ __launch_bounds__(256) void merge_mfma(const float* __restrict__ x,
    const ushort_t* __restrict__ mw,   // [128 d][512 c] bf16
    const ushort_t* __restrict__ mb,
    float* __restrict__ src){
  __shared__ ushort_t xt[2][64*128];   // 2 x 16KB, SWZ3-swizzled [64 q][128 c]
  const int tid = threadIdx.x;
  const int wave = tid >> 6, lane = tid & 63;
  const int lr = lane & 15, kg = lane >> 4;
  const int q0 = blockIdx.x * 64;
  const int qq4 = (tid & 15) * 4;      // 4 consecutive q per thread
  const int c8  = (tid >> 4) * 8;      // 8 consecutive c per thread (within chunk)
  const int qrow = wave*16 + lr;

  f32x4 v[8];
  #pragma unroll
  for (int cc=0;cc<8;cc++)
    v[cc] = *(const f32x4*)(x + (size_t)(c8 + cc)*Q_TOT + q0 + qq4);
  #pragma unroll
  for (int qq=0;qq<4;qq++){
    int row = qq4 + qq;
    u16x8 pk;
    #pragma unroll
    for (int cc=0;cc<8;cc++) pk[cc] = f2b(v[cc][qq]);
    *(u16x8*)((char*)xt[0] + SWZ3(row, row*256 + c8*2)) = pk;
  }
  __syncthreads();

  f32x4 acc[8];
  #pragma unroll
  for (int dt=0; dt<8; dt++) acc[dt] = (f32x4){0.f,0.f,0.f,0.f};

  for (int ch = 0; ch < 4; ch++){
    f32x4 v2[8];
    if (ch < 3){   // issue next chunk's loads BEFORE the MFMA burst
      #pragma unroll
      for (int cc=0;cc<8;cc++)
        v2[cc] = *(const f32x4*)(x + (size_t)((ch+1)*128 + c8 + cc)*Q_TOT + q0 + qq4);
    }
    const ushort_t* xb = xt[ch & 1];
    #pragma unroll
    for (int dt=0; dt<8; dt++){
      const int drow = dt*16 + lr;
      #pragma unroll
      for (int ks=0; ks<4; ks++){
        short8 wf = *(const short8*)(mw + (size_t)drow*512 + ch*128 + ks*32 + kg*8);
        short8 xf = *(const short8*)((const char*)xb + SWZ3(qrow, qrow*256 + (ks*32 + kg*8)*2));
        acc[dt] = __builtin_amdgcn_mfma_f32_16x16x32_bf16(xf, wf, acc[dt], 0, 0, 0);
      }
    }
    if (ch < 3){
      ushort_t* xn = xt[(ch+1) & 1];
      #pragma unroll
      for (int qq=0;qq<4;qq++){
        int row = qq4 + qq;
        u16x8 pk;
        #pragma unroll
        for (int cc=0;cc<8;cc++) pk[cc] = f2b(v2[cc][qq]);
        *(u16x8*)((char*)xn + SWZ3(row, row*256 + c8*2)) = pk;
      }
      __syncthreads();
    }
  }
  #pragma unroll
  for (int dt=0; dt<8; dt++){
    float bb = b2f(mb[dt*16 + lr]);
    #pragma unroll
    for (int r=0; r<4; r++){
      int q = q0 + wave*16 + kg*4 + r;
      float vv = acc[dt][r] + bb;
      src[(size_t)q*128 + dt*16 + lr] = vv > 0.f ? vv : 0.f;
    }
  }
}

// ---------------- offaw (MFMA): [off|aw] = (src+pos) @ oaw_t^T, softmax, loc ------
__global__ __launch_bounds__(256) void offaw_mfma(const float* __restrict__ src,
    const float* __restrict__ py, const float* __restrict__ px,
    const ushort_t* __restrict__ wt,   // [96 n][128 k] bf16
    const ushort_t* __restrict__ ob, const ushort_t* __restrict__ awb,
    float* __restrict__ loc, float* __restrict__ awg){
  __shared__ ushort_t qlds[64*128];    // 16KB swizzled
  const int tid = threadIdx.x;
  const int wave = tid >> 6, lane = tid & 63;
  const int lr = lane & 15, kg = lane >> 4;
  const int q0 = blockIdx.x * 64;
  { // stage q = src + pos(table)
    int row = tid >> 2, c0 = (tid & 3) * 32;
    int q = q0 + row, qy = q / W_, qx = q - qy*W_;
    const float* sp = src + (size_t)q*128 + c0;
    const float* tp = (c0 < 64) ? (py + qy*64 + c0) : (px + qx*64 + (c0 - 64));
    #pragma unroll
    for (int i=0;i<4;i++){
      f32x4 s0 = *(const f32x4*)(sp + i*8), s1 = *(const f32x4*)(sp + i*8 + 4);
      f32x4 t0 = *(const f32x4*)(tp + i*8), t1 = *(const f32x4*)(tp + i*8 + 4);
      u16x8 pk;
      #pragma unroll
      for (int j=0;j<4;j++){ pk[j] = f2b(s0[j]+t0[j]); pk[4+j] = f2b(s1[j]+t1[j]); }
      int byte = row*256 + (c0 + i*8)*2;
      *(u16x8*)((char*)qlds + SWZ(row, byte)) = pk;
    }
  }
  __syncthreads();
  const int qrow = wave*16 + lr;
  f32x4 acc[6];
  #pragma unroll
  for (int dt=0; dt<6; dt++) acc[dt] = (f32x4){0.f,0.f,0.f,0.f};
  #pragma unroll
  for (int dt=0; dt<6; dt++){
    const int nrow = dt*16 + lr;
    #pragma unroll
    for (int ks=0; ks<4; ks++){
      short8 wf = *(const short8*)(wt + (size_t)nrow*128 + ks*32 + kg*8);
      short8 xf = *(const short8*)((const char*)qlds + SWZ(qrow, qrow*256 + (ks*32 + kg*8)*2));
      acc[dt] = __builtin_amdgcn_mfma_f32_16x16x32_bf16(xf, wf, acc[dt], 0, 0, 0);
    }
  }
  #pragma unroll
  for (int r=0; r<4; r++){
    int q = q0 + wave*16 + kg*4 + r;
    int qy = q / W_, qx = q - qy*W_;
    float qxf = (float)qx, qyf = (float)qy;
    #pragma unroll
    for (int dt=0; dt<4; dt++){
      int n = dt*16 + lr;
      float v = acc[dt][r] + b2f(ob[n]);
      loc[(size_t)q*64 + n] = ((n & 1) ? qyf : qxf) + v;
    }
    #pragma unroll
    for (int d4=0; d4<2; d4++){
      int idx = d4*16 + lr;
      float v = acc[4+d4][r] + b2f(awb[idx]);
      float mx = fmaxf(v, __shfl_xor(v, 1, 64));
      mx = fmaxf(mx, __shfl_xor(mx, 2, 64));
      float e = expf(v - mx);
      float s = e + __shfl_xor(e, 1, 64);
      s = s + __shfl_xor(s, 2, 64);
      awg[(size_t)q*32 + idx] = e / s;
    }
  }
}

// ---------------- val = src @ val_w + b (MFMA) -> bf16 ----------------
__global__ __launch_bounds__(256) void val_mfma(const float* __restrict__ A,
    const ushort_t* __restrict__ wt,   // [128 n][128 k] bf16
    const ushort_t* __restrict__ bias,
    ushort_t* __restrict__ outv){
  __shared__ ushort_t a_lds[64*128];
  const int tid = threadIdx.x;
  const int wave = tid >> 6, lane = tid & 63;
  const int lr = lane & 15, kg = lane >> 4;
  const int q0 = blockIdx.x * 64;
  {
    int row = tid >> 2, c0 = (tid & 3) * 32;
    const float* sp = A + (size_t)(q0+row)*128 + c0;
    #pragma unroll
    for (int i=0;i<4;i++){
      f32x4 v0 = *(const f32x4*)(sp + i*8);
      f32x4 v1 = *(const f32x4*)(sp + i*8 + 4);
      u16x8 pk;
      #pragma unroll
      for (int j=0;j<4;j++){ pk[j]=f2b(v0[j]); pk[4+j]=f2b(v1[j]); }
      int byte = row*256 + (c0 + i*8)*2;
      *(u16x8*)((char*)a_lds + SWZ(row, byte)) = pk;
    }
  }
  __syncthreads();
  const int qrow = wave*16 + lr;
  f32x4 acc[8];
  #pragma unroll
  for (int dt=0; dt<8; dt++) acc[dt] = (f32x4){0.f,0.f,0.f,0.f};
  #pragma unroll
  for (int dt=0; dt<8; dt++){
    const int drow = dt*16 + lr;
    #pragma unroll
    for (int ks=0; ks<4; ks++){
      short8 yf = *(const short8*)(wt + (size_t)drow*128 + ks*32 + kg*8);
      short8 xf = *(const short8*)((const char*)a_lds + SWZ(qrow, qrow*256 + (ks*32 + kg*8)*2));
      acc[dt] = __builtin_amdgcn_mfma_f32_16x16x32_bf16(xf, yf, acc[dt], 0, 0, 0);
    }
  }
  #pragma unroll
  for (int dt=0; dt<8; dt++){
    float bb = b2f(bias[dt*16 + lr]);
    #pragma unroll
    for (int r=0; r<4; r++){
      int q = q0 + wave*16 + kg*4 + r;
      outv[(size_t)q*128 + dt*16 + lr] = f2b(acc[dt][r] + bb);
    }
  }
}

// ---------------- out-proj + residual + LN (MFMA), in-place on srcio ----------
__global__ __launch_bounds__(256) void outln_mfma(const float* __restrict__ A,
    const ushort_t* __restrict__ wt,   // [128 n][128 k] bf16
    const ushort_t* __restrict__ bias,
    const ushort_t* __restrict__ gs, const ushort_t* __restrict__ gb,
    float* srcio){
  __shared__ ushort_t a_lds[64*128];
  const int tid = threadIdx.x;
  const int wave = tid >> 6, lane = tid & 63;
  const int lr = lane & 15, kg = lane >> 4;
  const int q0 = blockIdx.x * 64;
  {
    int row = tid >> 2, c0 = (tid & 3) * 32;
    const float* sp = A + (size_t)(q0+row)*128 + c0;
    #pragma unroll
    for (int i=0;i<4;i++){
      f32x4 v0 = *(const f32x4*)(sp + i*8);
      f32x4 v1 = *(const f32x4*)(sp + i*8 + 4);
      u16x8 pk;
      #pragma unroll
      for (int j=0;j<4;j++){ pk[j]=f2b(v0[j]); pk[4+j]=f2b(v1[j]); }
      int byte = row*256 + (c0 + i*8)*2;
      *(u16x8*)((char*)a_lds + SWZ(row, byte)) = pk;
    }
  }
  __syncthreads();
  const int qrow = wave*16 + lr;
  f32x4 acc[8];
  #pragma unroll
  for (int dt=0; dt<8; dt++) acc[dt] = (f32x4){0.f,0.f,0.f,0.f};
  #pragma unroll
  for (int dt=0; dt<8; dt++){
    const int drow = dt*16 + lr;
    #pragma unroll
    for (int ks=0; ks<4; ks++){
      short8 yf = *(const short8*)(wt + (size_t)drow*128 + ks*32 + kg*8);
      short8 xf = *(const short8*)((const char*)a_lds + SWZ(qrow, qrow*256 + (ks*32 + kg*8)*2));
      acc[dt] = __builtin_amdgcn_mfma_f32_16x16x32_bf16(xf, yf, acc[dt], 0, 0, 0);
    }
  }
  float g4[8], be4[8], bi4[8];
  #pragma unroll
  for (int dt=0; dt<8; dt++){
    g4[dt] = b2f(gs[dt*16+lr]); be4[dt] = b2f(gb[dt*16+lr]); bi4[dt] = b2f(bias[dt*16+lr]);
  }
  #pragma unroll
  for (int r=0; r<4; r++){
    const int q = q0 + wave*16 + kg*4 + r;
    float vals[8];
    float s1 = 0.f, s2 = 0.f;
    #pragma unroll
    for (int dt=0; dt<8; dt++){
      float v = acc[dt][r] + bi4[dt] + srcio[(size_t)q*128 + dt*16 + lr];
      vals[dt] = v; s1 += v; s2 += v*v;
    }
    #pragma unroll
    for (int m=1; m<16; m<<=1){ s1 += __shfl_xor(s1, m, 64); s2 += __shfl_xor(s2, m, 64); }
    float mean = s1*(1.f/128.f);
    float var  = s2*(1.f/128.f) - mean*mean;
    float inv  = rsqrtf(var + 1e-5f);
    #pragma unroll
    for (int dt=0; dt<8; dt++)
      srcio[(size_t)q*128 + dt*16 + lr] = (vals[dt]-mean)*inv*g4[dt] + be4[dt];
  }
}

// ---------------- fused FFN + residual + LN (MFMA), in-place on srcio ----------
__global__ __launch_bounds__(256) void ffn_mfma(
    const ushort_t* __restrict__ w1t,  // [512 n][128 k] bf16
    const ushort_t* __restrict__ b1,
    const ushort_t* __restrict__ w2t,  // [128 n][512 k] bf16
    const ushort_t* __restrict__ b2,
    const ushort_t* __restrict__ gs, const ushort_t* __restrict__ gb,
    float* srcio){
  __shared__ ushort_t a_lds[64*128];   // 16KB swizzled, rows 256B
  __shared__ ushort_t h_lds[64*256];   // 32KB swizzled, rows 512B (one N-half)
  const int tid = threadIdx.x;
  const int wave = tid >> 6, lane = tid & 63;
  const int lr = lane & 15, kg = lane >> 4;
  const int q0 = blockIdx.x * 64;
  {
    int row = tid >> 2, c0 = (tid & 3) * 32;
    const float* sp = srcio + (size_t)(q0+row)*128 + c0;
    #pragma unroll
    for (int i=0;i<4;i++){
      f32x4 v0 = *(const f32x4*)(sp + i*8);
      f32x4 v1 = *(const f32x4*)(sp + i*8 + 4);
      u16x8 pk;
      #pragma unroll
      for (int j=0;j<4;j++){ pk[j]=f2b(v0[j]); pk[4+j]=f2b(v1[j]); }
      int byte = row*256 + (c0 + i*8)*2;
      *(u16x8*)((char*)a_lds + SWZ(row, byte)) = pk;
    }
  }
  __syncthreads();
  f32x4 accd[8];
  #pragma unroll
  for (int dt=0; dt<8; dt++) accd[dt] = (f32x4){0.f,0.f,0.f,0.f};
  for (int half=0; half<2; half++){
    for (int nt=0; nt<4; nt++){
      const int ngt = half*16 + wave*4 + nt;
      const int nrow = ngt*16 + lr;
      short8 xf[4];
      #pragma unroll
      for (int ks=0; ks<4; ks++)
        xf[ks] = *(const short8*)(w1t + (size_t)nrow*128 + ks*32 + kg*8);
      u16x4 bb = *(const u16x4*)(b1 + ngt*16 + kg*4);
      float bf[4];
      #pragma unroll
      for (int j=0;j<4;j++) bf[j] = b2f(bb[j]);
      #pragma unroll
      for (int qt=0; qt<4; qt++){
        f32x4 acc = (f32x4){0.f,0.f,0.f,0.f};
        const int q = qt*16 + lr;
        #pragma unroll
        for (int ks=0; ks<4; ks++){
          short8 yf = *(const short8*)((const char*)a_lds + SWZ(q, q*256 + (ks*32 + kg*8)*2));
          acc = __builtin_amdgcn_mfma_f32_16x16x32_bf16(xf[ks], yf, acc, 0, 0, 0);
        }
        const int nl = (ngt & 15)*16 + kg*4;
        u16x4 hp;
        #pragma unroll
        for (int r=0;r<4;r++){ float v = acc[r] + bf[r]; hp[r] = f2b(v > 0.f ? v : 0.f); }
        *(u16x4*)((char*)h_lds + SWZ(q, q*512 + nl*2)) = hp;
      }
    }
    __syncthreads();
    const int qrow = wave*16 + lr;
    #pragma unroll
    for (int dt=0; dt<8; dt++){
      const int drow = dt*16 + lr;
      #pragma unroll
      for (int ks=0; ks<8; ks++){
        short8 yf = *(const short8*)(w2t + (size_t)drow*512 + half*256 + ks*32 + kg*8);
        short8 xf2 = *(const short8*)((const char*)h_lds + SWZ(qrow, qrow*512 + (ks*32 + kg*8)*2));
        accd[dt] = __builtin_amdgcn_mfma_f32_16x16x32_bf16(xf2, yf, accd[dt], 0, 0, 0);
      }
    }
    __syncthreads();
  }
  float g4[8], be4[8], bi4[8];
  #pragma unroll
  for (int dt=0; dt<8; dt++){
    g4[dt] = b2f(gs[dt*16+lr]); be4[dt] = b2f(gb[dt*16+lr]); bi4[dt] = b2f(b2[dt*16+lr]);
  }
  #pragma unroll
  for (int r=0; r<4; r++){
    const int q = q0 + wave*16 + kg*4 + r;
    float vals[8];
    float s1 = 0.f, s2 = 0.f;
    #pragma unroll
    for (int dt=0; dt<8; dt++){
      float v = accd[dt][r] + bi4[dt] + srcio[(size_t)q*128 + dt*16 + lr];
      vals[dt] = v; s1 += v; s2 += v*v;
    }
    #pragma unroll
    for (int m=1; m<16; m<<=1){ s1 += __shfl_xor(s1, m, 64); s2 += __shfl_xor(s2, m, 64); }
    float mean = s1*(1.f/128.f);
    float var  = s2*(1.f/128.f) - mean*mean;
    float inv  = rsqrtf(var + 1e-5f);
    #pragma unroll
    for (int dt=0; dt<8; dt++)
      srcio[(size_t)q*128 + dt*16 + lr] = (vals[dt]-mean)*inv*g4[dt] + be4[dt];
  }
}

// ---------------- deformable bilinear sampling (bf16 val) ----------------
__global__ __launch_bounds__(256) void sample_kernel(const ushort_t* __restrict__ val,
    const float* __restrict__ loc, const float* __restrict__ awg,
    float* __restrict__ o){
  __shared__ float sl[2][64];
  __shared__ float sa[2][32];
  const int tid = threadIdx.x;
  const int q0 = blockIdx.x * 2;
  if (tid < 128){ sl[tid>>6][tid&63] = loc[(size_t)q0*64 + tid]; }
  else if (tid < 192){ int t = tid-128; sa[t>>5][t&31] = awg[(size_t)q0*32 + t]; }
  __syncthreads();
  const int ql = tid >> 7, c = tid & 127;
  const int h = c >> 4;
  float acc = 0.f;
  #pragma unroll
  for (int p=0;p<4;p++){
    float x = sl[ql][h*8 + p*2];
    float y = sl[ql][h*8 + p*2 + 1];
    float wgt = sa[ql][h*4 + p];
    float x0f = floorf(x), y0f = floorf(y);
    float wx = x - x0f, wy = y - y0f;
    int ix = (int)x0f, iy = (int)y0f;
    float s = 0.f;
    #pragma unroll
    for (int dy=0;dy<2;dy++){
      int yy = iy + dy;
      if (yy < 0 || yy >= H_) continue;
      float wyv = dy ? wy : 1.f - wy;
      #pragma unroll
      for (int dx=0;dx<2;dx++){
        int xx = ix + dx;
        if (xx < 0 || xx >= W_) continue;
        float wxv = dx ? wx : 1.f - wx;
        s += wyv*wxv*b2f(val[(size_t)(yy*W_ + xx)*128 + c]);
      }
    }
    acc += wgt * s;
  }
  o[(size_t)(q0+ql)*128 + c] = acc;
}

// ---------------- outc (MFMA): relu(src @ outc_w^T + b) -> fp32 [D][Q] ----------
__global__ __launch_bounds__(256) void outc_mfma(const float* __restrict__ A,
    const ushort_t* __restrict__ wt,   // outc_w [128 d][128 c] bf16 (row-major = [n][k])
    const ushort_t* __restrict__ bias,
    float* __restrict__ outp){
  __shared__ ushort_t a_lds[64*128];
  const int tid = threadIdx.x;
  const int wave = tid >> 6, lane = tid & 63;
  const int lr = lane & 15, kg = lane >> 4;
  const int q0 = blockIdx.x * 64;
  {
    int row = tid >> 2, c0 = (tid & 3) * 32;
    const float* sp = A + (size_t)(q0+row)*128 + c0;
    #pragma unroll
    for (int i=0;i<4;i++){
      f32x4 v0 = *(const f32x4*)(sp + i*8);
      f32x4 v1 = *(const f32x4*)(sp + i*8 + 4);
      u16x8 pk;
      #pragma unroll
      for (int j=0;j<4;j++){ pk[j]=f2b(v0[j]); pk[4+j]=f2b(v1[j]); }
      int byte = row*256 + (c0 + i*8)*2;
      *(u16x8*)((char*)a_lds + SWZ(row, byte)) = pk;
    }
  }
  __syncthreads();
  const int qrow = wave*16 + lr;
  f32x4 acc[8];
  #pragma unroll
  for (int dt=0; dt<8; dt++) acc[dt] = (f32x4){0.f,0.f,0.f,0.f};
  #pragma unroll
  for (int dt=0; dt<8; dt++){
    const int drow = dt*16 + lr;
    #pragma unroll
    for (int ks=0; ks<4; ks++){
      short8 yf = *(const short8*)(wt + (size_t)drow*128 + ks*32 + kg*8);
      short8 xf = *(const short8*)((const char*)a_lds + SWZ(qrow, qrow*256 + (ks*32 + kg*8)*2));
      acc[dt] = __builtin_amdgcn_mfma_f32_16x16x32_bf16(xf, yf, acc[dt], 0, 0, 0);
    }
  }
  #pragma unroll
  for (int dt=0; dt<8; dt++){
    float bb = b2f(bias[dt*16 + lr]);
    #pragma unroll
    for (int r=0; r<4; r++){
      int q = q0 + wave*16 + kg*4 + r;
      float v = acc[dt][r] + bb;
      v = v > 0.f ? v : 0.f;
      outp[(size_t)(dt*16 + lr)*Q_TOT + q] = v;   // [D][Q] scatter: 16B segments
    }
  }
}

extern "C" void kernel_launch(void* const* d_in, const int* in_sizes, int n_in,
                              void* d_out, int out_size, void* d_ws, size_t ws_size,
                              hipStream_t stream){
  const float* x = (const float*)d_in[0];

  float* src = (float*)d_ws;
  float* loc = src + (size_t)Q_TOT*128;
  float* aw  = loc + (size_t)Q_TOT*64;
  float* o   = aw  + (size_t)Q_TOT*32;
  ushort_t* valbf = (ushort_t*)(o + (size_t)Q_TOT*128);
  ushort_t* wbf   = valbf + (size_t)Q_TOT*128;
  ushort_t* tbase = wbf + 615072;
  float* postab = (float*)(tbase + 528384);
  float* pytab = postab;
  float* pxtab = postab + 120*64;

  // straight bf16 copies
  const ushort_t* mw     = wbf + 0;
  const ushort_t* mb     = wbf + 65536;
  const ushort_t* off_b  = wbf + 90240;
  const ushort_t* aw_b   = wbf + 102720;
  const ushort_t* val_b  = wbf + 151968;
  const ushort_t* out_b  = wbf + 201504;
  const ushort_t* n1_s   = wbf + 201888;
  const ushort_t* n1_b   = wbf + 202272;
  const ushort_t* l1_b   = wbf + 399264;
  const ushort_t* l2_b   = wbf + 597408;
  const ushort_t* n2_s   = wbf + 597792;
  const ushort_t* n2_b   = wbf + 598176;
  const ushort_t* outc_w = wbf + 598560;
  const ushort_t* outc_b = wbf + 614944;
  // transposed bf16 [N][K]
  const ushort_t* val_wt = tbase + 0;       // 3 x [128][128]
  const ushort_t* out_wt = tbase + 49152;   // 3 x [128][128]
  const ushort_t* l1_wt  = tbase + 98304;   // 3 x [512][128]
  const ushort_t* l2_wt  = tbase + 294912;  // 3 x [128][512]
  const ushort_t* oaw_t  = tbase + 491520;  // 3 x [96][128]

  cvt_kernel<<<(CVT_TOT+255)/256, 256, 0, stream>>>(
      (const float*)d_in[1],  (const float*)d_in[2],  (const float*)d_in[3],
      (const float*)d_in[4],  (const float*)d_in[5],  (const float*)d_in[6],
      (const float*)d_in[7],  (const float*)d_in[8],  (const float*)d_in[9],
      (const float*)d_in[10], (const float*)d_in[11], (const float*)d_in[12],
      (const float*)d_in[13], (const float*)d_in[14], (const float*)d_in[15],
      (const float*)d_in[16], (const float*)d_in[17], (const float*)d_in[18],
      (const float*)d_in[19], (const float*)d_in[20], wbf);
  cvtT_kernel<<<CVTT_TOT/256, 256, 0, stream>>>(
      (const float*)d_in[7], (const float*)d_in[9],
      (const float*)d_in[13], (const float*)d_in[15],
      (const float*)d_in[3], (const float*)d_in[5], tbase);
  postab_kernel<<<120, 256, 0, stream>>>(postab);

  merge_mfma<<<Q_TOT/64, 256, 0, stream>>>(x, mw, mb, src);
  for (int l = 0; l < 3; l++){
    offaw_mfma<<<Q_TOT/64, 256, 0, stream>>>(src, pytab, pxtab,
        oaw_t + (size_t)l*96*128, off_b + (size_t)l*64, aw_b + (size_t)l*32,
        loc, aw);
    val_mfma<<<Q_TOT/64, 256, 0, stream>>>(src,
        val_wt + (size_t)l*128*128, val_b + (size_t)l*128, valbf);
    sample_kernel<<<Q_TOT/2, 256, 0, stream>>>(valbf, loc, aw, o);
    outln_mfma<<<Q_TOT/64, 256, 0, stream>>>(o,
        out_wt + (size_t)l*128*128, out_b + (size_t)l*128,
        n1_s + (size_t)l*128, n1_b + (size_t)l*128, src);
    ffn_mfma<<<Q_TOT/64, 256, 0, stream>>>(
        l1_wt + (size_t)l*512*128, l1_b + (size_t)l*512,
        l2_wt + (size_t)l*128*512, l2_b + (size_t)l*128,
        n2_s + (size_t)l*128, n2_b + (size_t)l*128, src);
  }
  outc_mfma<<<Q_TOT/64, 256, 0, stream>>>(src, outc_w, outc_b, (float*)d_out);
}

// Round 6
// 562.111 us; speedup vs baseline: 2.3683x; 1.1801x over previous
//
#include <hip/hip_runtime.h>
#include <hip/hip_bf16.h>
#include <math.h>

#define Q_TOT 43200
#define H_ 120
#define W_ 360

typedef unsigned short ushort_t;
typedef float f32x4 __attribute__((ext_vector_type(4)));
typedef float f32x2 __attribute__((ext_vector_type(2)));
typedef unsigned short u16x4 __attribute__((ext_vector_type(4)));
typedef unsigned short u16x8 __attribute__((ext_vector_type(8)));
using short8 = __attribute__((ext_vector_type(8))) short;

static __device__ __forceinline__ float b2f(unsigned short u){
  return __uint_as_float(((unsigned)u) << 16);
}
static __device__ __forceinline__ unsigned short f2b(float f){
  unsigned u = __float_as_uint(f);
  unsigned r = (u + 0x7fffu + ((u >> 16) & 1u)) >> 16;  // RNE
  return (unsigned short)r;
}

// XOR-swizzle byte addr bits 4-6 with row&7
#define SWZ(row, byte) ((byte) ^ (((row) & 7) << 4))
// merge variant (stage rows differ by 4 within a thread's writes)
#define SWZ3(row, byte) ((byte) ^ ((((row) ^ ((row) >> 3)) & 7) << 4))

// ---------------- fp32 -> bf16 straight weight conversion ----------------
#define CVT_TOT 615072
__global__ __launch_bounds__(256) void cvt_kernel(
    const float* p0, const float* p1, const float* p2, const float* p3,
    const float* p4, const float* p5, const float* p6, const float* p7,
    const float* p8, const float* p9, const float* p10, const float* p11,
    const float* p12, const float* p13, const float* p14, const float* p15,
    const float* p16, const float* p17, const float* p18, const float* p19,
    ushort_t* __restrict__ dst){
  const float* ps[20] = {p0,p1,p2,p3,p4,p5,p6,p7,p8,p9,p10,p11,p12,p13,p14,p15,p16,p17,p18,p19};
  const int offs[20] = {0,65536,65664,90240,90432,102720,102816,151968,152352,201504,
                        201888,202272,202656,399264,400800,597408,597792,598176,598560,614944};
  int gid = blockIdx.x*256 + threadIdx.x;
  if (gid >= CVT_TOT) return;
  int s = 0;
  #pragma unroll
  for (int i=1;i<20;i++) s += (gid >= offs[i]) ? 1 : 0;
  dst[gid] = f2b(ps[s][gid - offs[s]]);
}

// ---- fp32 [L][K][N] -> bf16 [L][N][K]; last segment fuses off_w|aw_w into [96][128]
#define CVTT_TOT 528384
__global__ __launch_bounds__(256) void cvtT_kernel(
    const float* __restrict__ vw, const float* __restrict__ ow,
    const float* __restrict__ w1, const float* __restrict__ w2,
    const float* __restrict__ offw, const float* __restrict__ aww,
    ushort_t* __restrict__ dst){
  int gid = blockIdx.x*256 + threadIdx.x;
  if (gid >= CVTT_TOT) return;
  if (gid >= 491520){           // oaw_t: per layer [96 n][128 k]
    int e = gid - 491520;
    int l = e / 12288, rem = e - l*12288;
    int n = rem >> 7, k = rem & 127;
    float v = (n < 64) ? offw[((size_t)l*128 + k)*64 + n]
                       : aww [((size_t)l*128 + k)*32 + (n-64)];
    dst[gid] = f2b(v);
    return;
  }
  const float* s; int K, N, off;
  if (gid < 49152)      { s = vw; K = 128; N = 128; off = 0; }
  else if (gid < 98304) { s = ow; K = 128; N = 128; off = 49152; }
  else if (gid < 294912){ s = w1; K = 128; N = 512; off = 98304; }
  else                  { s = w2; K = 512; N = 128; off = 294912; }
  int e = gid - off;
  int per = K*N;
  int l = e / per, rem = e - l*per;
  int n = rem / K, k = rem - n*K;
  dst[gid] = f2b(s[(size_t)l*per + (size_t)k*N + n]);
}

// ---------------- separable pos tables: py[120][64] | px[360][64] ----------------
__global__ __launch_bounds__(256) void postab_kernel(float* __restrict__ tab){
  int gid = blockIdx.x*256 + threadIdx.x;
  if (gid >= 480*64) return;
  int row = gid >> 6, k = gid & 63;
  int m = k >> 1;
  float t = powf(10000.0f, (float)m * (1.0f/32.0f));
  float e;
  if (row < 120) e = (float)(row+1)   * (6.283185307179586f/((float)H_+1e-6f));
  else           e = (float)(row-119) * (6.283185307179586f/((float)W_+1e-6f));
  float p = e / t;
  tab[gid] = (k & 1) ? cosf(p) : sinf(p);
}

// ---------------- merge v2 (MFMA + dbuf + prefetch) ----------------
__global__ __launch_bounds__(256) void merge_mfma(const float* __restrict__ x,
    const ushort_t* __restrict__ mw,   // [128 d][512 c] bf16
    const ushort_t* __restrict__ mb,
    float* __restrict__ src){
  __shared__ ushort_t xt[2][64*128];
  const int tid = threadIdx.x;
  const int wave = tid >> 6, lane = tid & 63;
  const int lr = lane & 15, kg = lane >> 4;
  const int q0 = blockIdx.x * 64;
  const int qq4 = (tid & 15) * 4;
  const int c8  = (tid >> 4) * 8;
  const int qrow = wave*16 + lr;

  f32x4 v[8];
  #pragma unroll
  for (int cc=0;cc<8;cc++)
    v[cc] = *(const f32x4*)(x + (size_t)(c8 + cc)*Q_TOT + q0 + qq4);
  #pragma unroll
  for (int qq=0;qq<4;qq++){
    int row = qq4 + qq;
    u16x8 pk;
    #pragma unroll
    for (int cc=0;cc<8;cc++) pk[cc] = f2b(v[cc][qq]);
    *(u16x8*)((char*)xt[0] + SWZ3(row, row*256 + c8*2)) = pk;
  }
  __syncthreads();

  f32x4 acc[8];
  #pragma unroll
  for (int dt=0; dt<8; dt++) acc[dt] = (f32x4){0.f,0.f,0.f,0.f};

  for (int ch = 0; ch < 4; ch++){
    f32x4 v2[8];
    if (ch < 3){
      #pragma unroll
      for (int cc=0;cc<8;cc++)
        v2[cc] = *(const f32x4*)(x + (size_t)((ch+1)*128 + c8 + cc)*Q_TOT + q0 + qq4);
    }
    const ushort_t* xb = xt[ch & 1];
    #pragma unroll
    for (int dt=0; dt<8; dt++){
      const int drow = dt*16 + lr;
      #pragma unroll
      for (int ks=0; ks<4; ks++){
        short8 wf = *(const short8*)(mw + (size_t)drow*512 + ch*128 + ks*32 + kg*8);
        short8 xf = *(const short8*)((const char*)xb + SWZ3(qrow, qrow*256 + (ks*32 + kg*8)*2));
        acc[dt] = __builtin_amdgcn_mfma_f32_16x16x32_bf16(xf, wf, acc[dt], 0, 0, 0);
      }
    }
    if (ch < 3){
      ushort_t* xn = xt[(ch+1) & 1];
      #pragma unroll
      for (int qq=0;qq<4;qq++){
        int row = qq4 + qq;
        u16x8 pk;
        #pragma unroll
        for (int cc=0;cc<8;cc++) pk[cc] = f2b(v2[cc][qq]);
        *(u16x8*)((char*)xn + SWZ3(row, row*256 + c8*2)) = pk;
      }
      __syncthreads();
    }
  }
  #pragma unroll
  for (int dt=0; dt<8; dt++){
    float bb = b2f(mb[dt*16 + lr]);
    #pragma unroll
    for (int r=0; r<4; r++){
      int q = q0 + wave*16 + kg*4 + r;
      float vv = acc[dt][r] + bb;
      src[(size_t)q*128 + dt*16 + lr] = vv > 0.f ? vv : 0.f;
    }
  }
}

// ------- fused qv: offaw ([96] from src+pos) + val ([128] -> bf16 from src) -------
__global__ __launch_bounds__(256) void qv_mfma(const float* __restrict__ src,
    const float* __restrict__ py, const float* __restrict__ px,
    const ushort_t* __restrict__ owt,  // [96 n][128 k] bf16
    const ushort_t* __restrict__ ob, const ushort_t* __restrict__ awb,
    const ushort_t* __restrict__ vwt,  // [128 n][128 k] bf16
    const ushort_t* __restrict__ vb,
    float* __restrict__ loc, float* __restrict__ awg,
    ushort_t* __restrict__ valbf){
  __shared__ ushort_t a_lds[64*128];   // plain src (swizzled)
  __shared__ ushort_t qlds[64*128];    // src + pos (swizzled)
  const int tid = threadIdx.x;
  const int wave = tid >> 6, lane = tid & 63;
  const int lr = lane & 15, kg = lane >> 4;
  const int q0 = blockIdx.x * 64;
  { // stage both tiles from one src read
    int row = tid >> 2, c0 = (tid & 3) * 32;
    int q = q0 + row, qy = q / W_, qx = q - qy*W_;
    const float* sp = src + (size_t)q*128 + c0;
    const float* tp = (c0 < 64) ? (py + qy*64 + c0) : (px + qx*64 + (c0 - 64));
    #pragma unroll
    for (int i=0;i<4;i++){
      f32x4 s0 = *(const f32x4*)(sp + i*8), s1 = *(const f32x4*)(sp + i*8 + 4);
      f32x4 t0 = *(const f32x4*)(tp + i*8), t1 = *(const f32x4*)(tp + i*8 + 4);
      u16x8 pa, pq;
      #pragma unroll
      for (int j=0;j<4;j++){
        pa[j] = f2b(s0[j]);        pa[4+j] = f2b(s1[j]);
        pq[j] = f2b(s0[j]+t0[j]);  pq[4+j] = f2b(s1[j]+t1[j]);
      }
      int byte = row*256 + (c0 + i*8)*2;
      *(u16x8*)((char*)a_lds + SWZ(row, byte)) = pa;
      *(u16x8*)((char*)qlds + SWZ(row, byte)) = pq;
    }
  }
  __syncthreads();
  const int qrow = wave*16 + lr;
  f32x4 va[8], qa[6];
  #pragma unroll
  for (int dt=0; dt<8; dt++) va[dt] = (f32x4){0.f,0.f,0.f,0.f};
  #pragma unroll
  for (int nt=0; nt<6; nt++) qa[nt] = (f32x4){0.f,0.f,0.f,0.f};
  #pragma unroll
  for (int dt=0; dt<8; dt++){
    const int drow = dt*16 + lr;
    #pragma unroll
    for (int ks=0; ks<4; ks++){
      short8 yf = *(const short8*)(vwt + (size_t)drow*128 + ks*32 + kg*8);
      short8 xf = *(const short8*)((const char*)a_lds + SWZ(qrow, qrow*256 + (ks*32 + kg*8)*2));
      va[dt] = __builtin_amdgcn_mfma_f32_16x16x32_bf16(xf, yf, va[dt], 0, 0, 0);
    }
  }
  #pragma unroll
  for (int nt=0; nt<6; nt++){
    const int nrow = nt*16 + lr;
    #pragma unroll
    for (int ks=0; ks<4; ks++){
      short8 wf = *(const short8*)(owt + (size_t)nrow*128 + ks*32 + kg*8);
      short8 xq = *(const short8*)((const char*)qlds + SWZ(qrow, qrow*256 + (ks*32 + kg*8)*2));
      qa[nt] = __builtin_amdgcn_mfma_f32_16x16x32_bf16(xq, wf, qa[nt], 0, 0, 0);
    }
  }
  // val epilogue -> bf16
  #pragma unroll
  for (int dt=0; dt<8; dt++){
    float bb = b2f(vb[dt*16 + lr]);
    #pragma unroll
    for (int r=0; r<4; r++){
      int q = q0 + wave*16 + kg*4 + r;
      valbf[(size_t)q*128 + dt*16 + lr] = f2b(va[dt][r] + bb);
    }
  }
  // offaw epilogue: loc + softmax(aw)
  #pragma unroll
  for (int r=0; r<4; r++){
    int q = q0 + wave*16 + kg*4 + r;
    int qy = q / W_, qx = q - qy*W_;
    float qxf = (float)qx, qyf = (float)qy;
    #pragma unroll
    for (int dt=0; dt<4; dt++){
      int n = dt*16 + lr;
      float v = qa[dt][r] + b2f(ob[n]);
      loc[(size_t)q*64 + n] = ((n & 1) ? qyf : qxf) + v;
    }
    #pragma unroll
    for (int d4=0; d4<2; d4++){
      int idx = d4*16 + lr;
      float v = qa[4+d4][r] + b2f(awb[idx]);
      float mx = fmaxf(v, __shfl_xor(v, 1, 64));
      mx = fmaxf(mx, __shfl_xor(mx, 2, 64));
      float e = expf(v - mx);
      float s = e + __shfl_xor(e, 1, 64);
      s = s + __shfl_xor(s, 2, 64);
      awg[(size_t)q*32 + idx] = e / s;
    }
  }
}

// ---------------- out-proj + residual + LN (MFMA), in-place on srcio ----------
__global__ __launch_bounds__(256) void outln_mfma(const float* __restrict__ A,
    const ushort_t* __restrict__ wt,   // [128 n][128 k] bf16
    const ushort_t* __restrict__ bias,
    const ushort_t* __restrict__ gs, const ushort_t* __restrict__ gb,
    float* srcio){
  __shared__ ushort_t a_lds[64*128];
  const int tid = threadIdx.x;
  const int wave = tid >> 6, lane = tid & 63;
  const int lr = lane & 15, kg = lane >> 4;
  const int q0 = blockIdx.x * 64;
  {
    int row = tid >> 2, c0 = (tid & 3) * 32;
    const float* sp = A + (size_t)(q0+row)*128 + c0;
    #pragma unroll
    for (int i=0;i<4;i++){
      f32x4 v0 = *(const f32x4*)(sp + i*8);
      f32x4 v1 = *(const f32x4*)(sp + i*8 + 4);
      u16x8 pk;
      #pragma unroll
      for (int j=0;j<4;j++){ pk[j]=f2b(v0[j]); pk[4+j]=f2b(v1[j]); }
      int byte = row*256 + (c0 + i*8)*2;
      *(u16x8*)((char*)a_lds + SWZ(row, byte)) = pk;
    }
  }
  __syncthreads();
  const int qrow = wave*16 + lr;
  f32x4 acc[8];
  #pragma unroll
  for (int dt=0; dt<8; dt++) acc[dt] = (f32x4){0.f,0.f,0.f,0.f};
  #pragma unroll
  for (int dt=0; dt<8; dt++){
    const int drow = dt*16 + lr;
    #pragma unroll
    for (int ks=0; ks<4; ks++){
      short8 yf = *(const short8*)(wt + (size_t)drow*128 + ks*32 + kg*8);
      short8 xf = *(const short8*)((const char*)a_lds + SWZ(qrow, qrow*256 + (ks*32 + kg*8)*2));
      acc[dt] = __builtin_amdgcn_mfma_f32_16x16x32_bf16(xf, yf, acc[dt], 0, 0, 0);
    }
  }
  float g4[8], be4[8], bi4[8];
  #pragma unroll
  for (int dt=0; dt<8; dt++){
    g4[dt] = b2f(gs[dt*16+lr]); be4[dt] = b2f(gb[dt*16+lr]); bi4[dt] = b2f(bias[dt*16+lr]);
  }
  #pragma unroll
  for (int r=0; r<4; r++){
    const int q = q0 + wave*16 + kg*4 + r;
    float vals[8];
    float s1 = 0.f, s2 = 0.f;
    #pragma unroll
    for (int dt=0; dt<8; dt++){
      float v = acc[dt][r] + bi4[dt] + srcio[(size_t)q*128 + dt*16 + lr];
      vals[dt] = v; s1 += v; s2 += v*v;
    }
    #pragma unroll
    for (int m=1; m<16; m<<=1){ s1 += __shfl_xor(s1, m, 64); s2 += __shfl_xor(s2, m, 64); }
    float mean = s1*(1.f/128.f);
    float var  = s2*(1.f/128.f) - mean*mean;
    float inv  = rsqrtf(var + 1e-5f);
    #pragma unroll
    for (int dt=0; dt<8; dt++)
      srcio[(size_t)q*128 + dt*16 + lr] = (vals[dt]-mean)*inv*g4[dt] + be4[dt];
  }
}

// ------------- fused FFN + residual + LN (MFMA, 8 waves), in-place -------------
__global__ __launch_bounds__(512) void ffn_mfma(
    const ushort_t* __restrict__ w1t,  // [512 n][128 k] bf16
    const ushort_t* __restrict__ b1,
    const ushort_t* __restrict__ w2t,  // [128 n][512 k] bf16
    const ushort_t* __restrict__ b2,
    const ushort_t* __restrict__ gs, const ushort_t* __restrict__ gb,
    float* srcio){
  __shared__ ushort_t a_lds[64*128];   // 16KB swizzled; reused as f32 scratch in epilogue
  __shared__ ushort_t h_lds[64*256];   // 32KB swizzled (one N-half)
  const int tid = threadIdx.x;
  const int wave = tid >> 6, lane = tid & 63;
  const int lr = lane & 15, kg = lane >> 4;
  const int q0 = blockIdx.x * 64;
  { // stage with 512 threads
    int row = tid >> 3, c0 = (tid & 7) * 16;
    const float* sp = srcio + (size_t)(q0+row)*128 + c0;
    #pragma unroll
    for (int i=0;i<2;i++){
      f32x4 v0 = *(const f32x4*)(sp + i*8);
      f32x4 v1 = *(const f32x4*)(sp + i*8 + 4);
      u16x8 pk;
      #pragma unroll
      for (int j=0;j<4;j++){ pk[j]=f2b(v0[j]); pk[4+j]=f2b(v1[j]); }
      int byte = row*256 + (c0 + i*8)*2;
      *(u16x8*)((char*)a_lds + SWZ(row, byte)) = pk;
    }
  }
  __syncthreads();
  const int qt2 = wave & 3, dh = wave >> 2;   // GEMM2 role: q-tile, dt-half
  f32x4 accd[4];
  #pragma unroll
  for (int dtl=0; dtl<4; dtl++) accd[dtl] = (f32x4){0.f,0.f,0.f,0.f};
  for (int half=0; half<2; half++){
    // GEMM1: wave handles 2 n-tiles; D[n][q] so relu+pack writes land [q][n]
    #pragma unroll
    for (int nt=0; nt<2; nt++){
      const int ngt = half*16 + wave*2 + nt;
      const int nrow = ngt*16 + lr;
      short8 xf[4];
      #pragma unroll
      for (int ks=0; ks<4; ks++)
        xf[ks] = *(const short8*)(w1t + (size_t)nrow*128 + ks*32 + kg*8);
      u16x4 bb = *(const u16x4*)(b1 + ngt*16 + kg*4);
      float bf[4];
      #pragma unroll
      for (int j=0;j<4;j++) bf[j] = b2f(bb[j]);
      #pragma unroll
      for (int qt=0; qt<4; qt++){
        f32x4 acc = (f32x4){0.f,0.f,0.f,0.f};
        const int q = qt*16 + lr;
        #pragma unroll
        for (int ks=0; ks<4; ks++){
          short8 yf = *(const short8*)((const char*)a_lds + SWZ(q, q*256 + (ks*32 + kg*8)*2));
          acc = __builtin_amdgcn_mfma_f32_16x16x32_bf16(xf[ks], yf, acc, 0, 0, 0);
        }
        const int nl = (ngt & 15)*16 + kg*4;
        u16x4 hp;
        #pragma unroll
        for (int r=0;r<4;r++){ float v = acc[r] + bf[r]; hp[r] = f2b(v > 0.f ? v : 0.f); }
        *(u16x4*)((char*)h_lds + SWZ(q, q*512 + nl*2)) = hp;
      }
    }
    __syncthreads();
    // GEMM2 partial: wave (qt2, dh), 4 dt x 8 ks
    const int qrow = qt2*16 + lr;
    #pragma unroll
    for (int dtl=0; dtl<4; dtl++){
      const int drow = (dh*4 + dtl)*16 + lr;
      #pragma unroll
      for (int ks=0; ks<8; ks++){
        short8 yf = *(const short8*)(w2t + (size_t)drow*512 + half*256 + ks*32 + kg*8);
        short8 xf2 = *(const short8*)((const char*)h_lds + SWZ(qrow, qrow*512 + (ks*32 + kg*8)*2));
        accd[dtl] = __builtin_amdgcn_mfma_f32_16x16x32_bf16(xf2, yf, accd[dtl], 0, 0, 0);
      }
    }
    __syncthreads();
  }
  // epilogue: waves 4-7 dump dt 4-7 to scratch; waves 0-3 do residual+LN
  float* scr = (float*)a_lds;   // [64][64] f32 = 16KB
  if (wave >= 4){
    #pragma unroll
    for (int dtl=0; dtl<4; dtl++)
      #pragma unroll
      for (int r=0; r<4; r++)
        scr[(qt2*16 + kg*4 + r)*64 + dtl*16 + lr] = accd[dtl][r];
  }
  __syncthreads();
  if (wave < 4){
    float g4[8], be4[8], bi4[8];
    #pragma unroll
    for (int dt=0; dt<8; dt++){
      g4[dt] = b2f(gs[dt*16+lr]); be4[dt] = b2f(gb[dt*16+lr]); bi4[dt] = b2f(b2[dt*16+lr]);
    }
    #pragma unroll
    for (int r=0; r<4; r++){
      const int q = q0 + qt2*16 + kg*4 + r;
      float vals[8];
      float s1 = 0.f, s2 = 0.f;
      #pragma unroll
      for (int dtl=0; dtl<4; dtl++){
        float v = accd[dtl][r] + bi4[dtl] + srcio[(size_t)q*128 + dtl*16 + lr];
        vals[dtl] = v; s1 += v; s2 += v*v;
      }
      #pragma unroll
      for (int dt=4; dt<8; dt++){
        float v = scr[(qt2*16 + kg*4 + r)*64 + (dt-4)*16 + lr]
                + bi4[dt] + srcio[(size_t)q*128 + dt*16 + lr];
        vals[dt] = v; s1 += v; s2 += v*v;
      }
      #pragma unroll
      for (int m=1; m<16; m<<=1){ s1 += __shfl_xor(s1, m, 64); s2 += __shfl_xor(s2, m, 64); }
      float mean = s1*(1.f/128.f);
      float var  = s2*(1.f/128.f) - mean*mean;
      float inv  = rsqrtf(var + 1e-5f);
      #pragma unroll
      for (int dt=0; dt<8; dt++)
        srcio[(size_t)q*128 + dt*16 + lr] = (vals[dt]-mean)*inv*g4[dt] + be4[dt];
    }
  }
}

// ---------------- deformable bilinear sampling (bf16 val, 4 q/block) ------------
__global__ __launch_bounds__(256) void sample_kernel(const ushort_t* __restrict__ val,
    const float* __restrict__ loc, const float* __restrict__ awg,
    float* __restrict__ o){
  __shared__ float sl[4][64];
  __shared__ float sa[4][32];
  const int tid = threadIdx.x;
  const int q0 = blockIdx.x * 4;
  sl[0][tid & 255] = loc[(size_t)q0*64 + tid];      // 256 floats
  if (tid < 128) sa[0][tid] = awg[(size_t)q0*32 + tid];
  __syncthreads();
  const int ql = tid >> 6, cp = (tid & 63) * 2;     // 2 channels per thread
  const int h = cp >> 4;
  float a0 = 0.f, a1 = 0.f;
  #pragma unroll
  for (int p=0;p<4;p++){
    float x = sl[ql][h*8 + p*2];
    float y = sl[ql][h*8 + p*2 + 1];
    float wgt = sa[ql][h*4 + p];
    float x0f = floorf(x), y0f = floorf(y);
    float wx = x - x0f, wy = y - y0f;
    int ix = (int)x0f, iy = (int)y0f;
    float s0 = 0.f, s1 = 0.f;
    #pragma unroll
    for (int dy=0;dy<2;dy++){
      int yy = iy + dy;
      if (yy < 0 || yy >= H_) continue;
      float wyv = dy ? wy : 1.f - wy;
      #pragma unroll
      for (int dx=0;dx<2;dx++){
        int xx = ix + dx;
        if (xx < 0 || xx >= W_) continue;
        float wxv = dx ? wx : 1.f - wx;
        const ushort_t* vp = val + (size_t)(yy*W_ + xx)*128 + cp;
        float wv = wyv*wxv;
        s0 += wv*b2f(vp[0]);
        s1 += wv*b2f(vp[1]);
      }
    }
    a0 += wgt * s0;
    a1 += wgt * s1;
  }
  f32x2 r; r[0] = a0; r[1] = a1;
  *(f32x2*)&o[(size_t)(q0+ql)*128 + cp] = r;
}

// ---------------- outc (MFMA): relu(src @ outc_w^T + b) -> fp32 [D][Q] ----------
__global__ __launch_bounds__(256) void outc_mfma(const float* __restrict__ A,
    const ushort_t* __restrict__ wt,   // outc_w [128 d][128 c] bf16 (= [n][k])
    const ushort_t* __restrict__ bias,
    float* __restrict__ outp){
  __shared__ ushort_t a_lds[64*128];
  const int tid = threadIdx.x;
  const int wave = tid >> 6, lane = tid & 63;
  const int lr = lane & 15, kg = lane >> 4;
  const int q0 = blockIdx.x * 64;
  {
    int row = tid >> 2, c0 = (tid & 3) * 32;
    const float* sp = A + (size_t)(q0+row)*128 + c0;
    #pragma unroll
    for (int i=0;i<4;i++){
      f32x4 v0 = *(const f32x4*)(sp + i*8);
      f32x4 v1 = *(const f32x4*)(sp + i*8 + 4);
      u16x8 pk;
      #pragma unroll
      for (int j=0;j<4;j++){ pk[j]=f2b(v0[j]); pk[4+j]=f2b(v1[j]); }
      int byte = row*256 + (c0 + i*8)*2;
      *(u16x8*)((char*)a_lds + SWZ(row, byte)) = pk;
    }
  }
  __syncthreads();
  const int qrow = wave*16 + lr;
  f32x4 acc[8];
  #pragma unroll
  for (int dt=0; dt<8; dt++) acc[dt] = (f32x4){0.f,0.f,0.f,0.f};
  #pragma unroll
  for (int dt=0; dt<8; dt++){
    const int drow = dt*16 + lr;
    #pragma unroll
    for (int ks=0; ks<4; ks++){
      short8 yf = *(const short8*)(wt + (size_t)drow*128 + ks*32 + kg*8);
      short8 xf = *(const short8*)((const char*)a_lds + SWZ(qrow, qrow*256 + (ks*32 + kg*8)*2));
      acc[dt] = __builtin_amdgcn_mfma_f32_16x16x32_bf16(xf, yf, acc[dt], 0, 0, 0);
    }
  }
  #pragma unroll
  for (int dt=0; dt<8; dt++){
    float bb = b2f(bias[dt*16 + lr]);
    #pragma unroll
    for (int r=0; r<4; r++){
      int q = q0 + wave*16 + kg*4 + r;
      float v = acc[dt][r] + bb;
      v = v > 0.f ? v : 0.f;
      outp[(size_t)(dt*16 + lr)*Q_TOT + q] = v;
    }
  }
}

extern "C" void kernel_launch(void* const* d_in, const int* in_sizes, int n_in,
                              void* d_out, int out_size, void* d_ws, size_t ws_size,
                              hipStream_t stream){
  const float* x = (const float*)d_in[0];

  float* src = (float*)d_ws;
  float* loc = src + (size_t)Q_TOT*128;
  float* aw  = loc + (size_t)Q_TOT*64;
  float* o   = aw  + (size_t)Q_TOT*32;
  ushort_t* valbf = (ushort_t*)(o + (size_t)Q_TOT*128);
  ushort_t* wbf   = valbf + (size_t)Q_TOT*128;
  ushort_t* tbase = wbf + 615072;
  float* postab = (float*)(tbase + 528384);
  float* pytab = postab;
  float* pxtab = postab + 120*64;

  const ushort_t* mw     = wbf + 0;
  const ushort_t* mb     = wbf + 65536;
  const ushort_t* off_b  = wbf + 90240;
  const ushort_t* aw_b   = wbf + 102720;
  const ushort_t* val_b  = wbf + 151968;
  const ushort_t* out_b  = wbf + 201504;
  const ushort_t* n1_s   = wbf + 201888;
  const ushort_t* n1_b   = wbf + 202272;
  const ushort_t* l1_b   = wbf + 399264;
  const ushort_t* l2_b   = wbf + 597408;
  const ushort_t* n2_s   = wbf + 597792;
  const ushort_t* n2_b   = wbf + 598176;
  const ushort_t* outc_w = wbf + 598560;
  const ushort_t* outc_b = wbf + 614944;
  const ushort_t* val_wt = tbase + 0;       // 3 x [128][128]
  const ushort_t* out_wt = tbase + 49152;   // 3 x [128][128]
  const ushort_t* l1_wt  = tbase + 98304;   // 3 x [512][128]
  const ushort_t* l2_wt  = tbase + 294912;  // 3 x [128][512]
  const ushort_t* oaw_t  = tbase + 491520;  // 3 x [96][128]

  cvt_kernel<<<(CVT_TOT+255)/256, 256, 0, stream>>>(
      (const float*)d_in[1],  (const float*)d_in[2],  (const float*)d_in[3],
      (const float*)d_in[4],  (const float*)d_in[5],  (const float*)d_in[6],
      (const float*)d_in[7],  (const float*)d_in[8],  (const float*)d_in[9],
      (const float*)d_in[10], (const float*)d_in[11], (const float*)d_in[12],
      (const float*)d_in[13], (const float*)d_in[14], (const float*)d_in[15],
      (const float*)d_in[16], (const float*)d_in[17], (const float*)d_in[18],
      (const float*)d_in[19], (const float*)d_in[20], wbf);
  cvtT_kernel<<<CVTT_TOT/256, 256, 0, stream>>>(
      (const float*)d_in[7], (const float*)d_in[9],
      (const float*)d_in[13], (const float*)d_in[15],
      (const float*)d_in[3], (const float*)d_in[5], tbase);
  postab_kernel<<<120, 256, 0, stream>>>(postab);

  merge_mfma<<<Q_TOT/64, 256, 0, stream>>>(x, mw, mb, src);
  for (int l = 0; l < 3; l++){
    qv_mfma<<<Q_TOT/64, 256, 0, stream>>>(src, pytab, pxtab,
        oaw_t + (size_t)l*96*128, off_b + (size_t)l*64, aw_b + (size_t)l*32,
        val_wt + (size_t)l*128*128, val_b + (size_t)l*128,
        loc, aw, valbf);
    sample_kernel<<<Q_TOT/4, 256, 0, stream>>>(valbf, loc, aw, o);
    outln_mfma<<<Q_TOT/64, 256, 0, stream>>>(o,
        out_wt + (size_t)l*128*128, out_b + (size_t)l*128,
        n1_s + (size_t)l*128, n1_b + (size_t)l*128, src);
    ffn_mfma<<<Q_TOT/64, 512, 0, stream>>>(
        l1_wt + (size_t)l*512*128, l1_b + (size_t)l*512,
        l2_wt + (size_t)l*128*512, l2_b + (size_t)l*128,
        n2_s + (size_t)l*128, n2_b + (size_t)l*128, src);
  }
  outc_mfma<<<Q_TOT/64, 256, 0, stream>>>(src, outc_w, outc_b, (float*)d_out);
}

// Round 7
// 416.250 us; speedup vs baseline: 3.1982x; 1.3504x over previous
//
#include <hip/hip_runtime.h>
#include <hip/hip_bf16.h>
#include <math.h>

#define Q_TOT 43200
#define H_ 120
#define W_ 360

typedef unsigned short ushort_t;
typedef float f32x4 __attribute__((ext_vector_type(4)));
typedef float f32x2 __attribute__((ext_vector_type(2)));
typedef unsigned short u16x4 __attribute__((ext_vector_type(4)));
typedef unsigned short u16x8 __attribute__((ext_vector_type(8)));
using short8 = __attribute__((ext_vector_type(8))) short;

static __device__ __forceinline__ float b2f(unsigned short u){
  return __uint_as_float(((unsigned)u) << 16);
}
static __device__ __forceinline__ unsigned short f2b(float f){
  unsigned u = __float_as_uint(f);
  unsigned r = (u + 0x7fffu + ((u >> 16) & 1u)) >> 16;  // RNE
  return (unsigned short)r;
}

#define SWZ(row, byte) ((byte) ^ (((row) & 7) << 4))
#define SWZ3(row, byte) ((byte) ^ ((((row) ^ ((row) >> 3)) & 7) << 4))

// ---------------- fp32 -> bf16 straight weight conversion ----------------
#define CVT_TOT 615072
__global__ __launch_bounds__(256) void cvt_kernel(
    const float* p0, const float* p1, const float* p2, const float* p3,
    const float* p4, const float* p5, const float* p6, const float* p7,
    const float* p8, const float* p9, const float* p10, const float* p11,
    const float* p12, const float* p13, const float* p14, const float* p15,
    const float* p16, const float* p17, const float* p18, const float* p19,
    ushort_t* __restrict__ dst){
  const float* ps[20] = {p0,p1,p2,p3,p4,p5,p6,p7,p8,p9,p10,p11,p12,p13,p14,p15,p16,p17,p18,p19};
  const int offs[20] = {0,65536,65664,90240,90432,102720,102816,151968,152352,201504,
                        201888,202272,202656,399264,400800,597408,597792,598176,598560,614944};
  int gid = blockIdx.x*256 + threadIdx.x;
  if (gid >= CVT_TOT) return;
  int s = 0;
  #pragma unroll
  for (int i=1;i<20;i++) s += (gid >= offs[i]) ? 1 : 0;
  dst[gid] = f2b(ps[s][gid - offs[s]]);
}

// ---- fp32 [L][K][N] -> bf16 [L][N][K]; last segment fuses off_w|aw_w into [96][128]
#define CVTT_TOT 528384
__global__ __launch_bounds__(256) void cvtT_kernel(
    const float* __restrict__ vw, const float* __restrict__ ow,
    const float* __restrict__ w1, const float* __restrict__ w2,
    const float* __restrict__ offw, const float* __restrict__ aww,
    ushort_t* __restrict__ dst){
  int gid = blockIdx.x*256 + threadIdx.x;
  if (gid >= CVTT_TOT) return;
  if (gid >= 491520){
    int e = gid - 491520;
    int l = e / 12288, rem = e - l*12288;
    int n = rem >> 7, k = rem & 127;
    float v = (n < 64) ? offw[((size_t)l*128 + k)*64 + n]
                       : aww [((size_t)l*128 + k)*32 + (n-64)];
    dst[gid] = f2b(v);
    return;
  }
  const float* s; int K, N, off;
  if (gid < 49152)      { s = vw; K = 128; N = 128; off = 0; }
  else if (gid < 98304) { s = ow; K = 128; N = 128; off = 49152; }
  else if (gid < 294912){ s = w1; K = 128; N = 512; off = 98304; }
  else                  { s = w2; K = 512; N = 128; off = 294912; }
  int e = gid - off;
  int per = K*N;
  int l = e / per, rem = e - l*per;
  int n = rem / K, k = rem - n*K;
  dst[gid] = f2b(s[(size_t)l*per + (size_t)k*N + n]);
}

// ---------------- separable pos tables: py[120][64] | px[360][64] ----------------
__global__ __launch_bounds__(256) void postab_kernel(float* __restrict__ tab){
  int gid = blockIdx.x*256 + threadIdx.x;
  if (gid >= 480*64) return;
  int row = gid >> 6, k = gid & 63;
  int m = k >> 1;
  float t = powf(10000.0f, (float)m * (1.0f/32.0f));
  float e;
  if (row < 120) e = (float)(row+1)   * (6.283185307179586f/((float)H_+1e-6f));
  else           e = (float)(row-119) * (6.283185307179586f/((float)W_+1e-6f));
  float p = e / t;
  tab[gid] = (k & 1) ? cosf(p) : sinf(p);
}

// ---------------- merge (MFMA + dbuf + prefetch + hoisted frags) ----------------
__global__ __launch_bounds__(256) void merge_mfma(const float* __restrict__ x,
    const ushort_t* __restrict__ mw,   // [128 d][512 c] bf16
    const ushort_t* __restrict__ mb,
    float* __restrict__ src){
  __shared__ ushort_t xt[2][64*128];
  const int tid = threadIdx.x;
  const int wave = tid >> 6, lane = tid & 63;
  const int lr = lane & 15, kg = lane >> 4;
  const int q0 = blockIdx.x * 64;
  const int qq4 = (tid & 15) * 4;
  const int c8  = (tid >> 4) * 8;
  const int qrow = wave*16 + lr;

  f32x4 v[8];
  #pragma unroll
  for (int cc=0;cc<8;cc++)
    v[cc] = *(const f32x4*)(x + (size_t)(c8 + cc)*Q_TOT + q0 + qq4);
  #pragma unroll
  for (int qq=0;qq<4;qq++){
    int row = qq4 + qq;
    u16x8 pk;
    #pragma unroll
    for (int cc=0;cc<8;cc++) pk[cc] = f2b(v[cc][qq]);
    *(u16x8*)((char*)xt[0] + SWZ3(row, row*256 + c8*2)) = pk;
  }
  __syncthreads();

  f32x4 acc[8];
  #pragma unroll
  for (int dt=0; dt<8; dt++) acc[dt] = (f32x4){0.f,0.f,0.f,0.f};

  for (int ch = 0; ch < 4; ch++){
    f32x4 v2[8];
    if (ch < 3){
      #pragma unroll
      for (int cc=0;cc<8;cc++)
        v2[cc] = *(const f32x4*)(x + (size_t)((ch+1)*128 + c8 + cc)*Q_TOT + q0 + qq4);
    }
    const ushort_t* xb = xt[ch & 1];
    short8 xfc[4];
    #pragma unroll
    for (int ks=0; ks<4; ks++)
      xfc[ks] = *(const short8*)((const char*)xb + SWZ3(qrow, qrow*256 + (ks*32 + kg*8)*2));
    short8 wfr[2][4];
    #pragma unroll
    for (int ks=0; ks<4; ks++)
      wfr[0][ks] = *(const short8*)(mw + (size_t)(lr)*512 + ch*128 + ks*32 + kg*8);
    #pragma unroll
    for (int dt=0; dt<8; dt++){
      if (dt < 7){
        const int nr = (dt+1)*16 + lr;
        #pragma unroll
        for (int ks=0; ks<4; ks++)
          wfr[(dt+1)&1][ks] = *(const short8*)(mw + (size_t)nr*512 + ch*128 + ks*32 + kg*8);
      }
      #pragma unroll
      for (int ks=0; ks<4; ks++)
        acc[dt] = __builtin_amdgcn_mfma_f32_16x16x32_bf16(xfc[ks], wfr[dt&1][ks], acc[dt], 0, 0, 0);
    }
    if (ch < 3){
      ushort_t* xn = xt[(ch+1) & 1];
      #pragma unroll
      for (int qq=0;qq<4;qq++){
        int row = qq4 + qq;
        u16x8 pk;
        #pragma unroll
        for (int cc=0;cc<8;cc++) pk[cc] = f2b(v2[cc][qq]);
        *(u16x8*)((char*)xn + SWZ3(row, row*256 + c8*2)) = pk;
      }
      __syncthreads();
    }
  }
  #pragma unroll
  for (int dt=0; dt<8; dt++){
    float bb = b2f(mb[dt*16 + lr]);
    #pragma unroll
    for (int r=0; r<4; r++){
      int q = q0 + wave*16 + kg*4 + r;
      float vv = acc[dt][r] + bb;
      src[(size_t)q*128 + dt*16 + lr] = vv > 0.f ? vv : 0.f;
    }
  }
}

// ------- fused qv: offaw + val, hoisted frags + weight prefetch -------
__global__ __launch_bounds__(256) void qv_mfma(const float* __restrict__ src,
    const float* __restrict__ py, const float* __restrict__ px,
    const ushort_t* __restrict__ owt,  // [96 n][128 k] bf16
    const ushort_t* __restrict__ ob, const ushort_t* __restrict__ awb,
    const ushort_t* __restrict__ vwt,  // [128 n][128 k] bf16
    const ushort_t* __restrict__ vb,
    float* __restrict__ loc, float* __restrict__ awg,
    ushort_t* __restrict__ valbf){
  __shared__ ushort_t a_lds[64*128];
  __shared__ ushort_t qlds[64*128];
  const int tid = threadIdx.x;
  const int wave = tid >> 6, lane = tid & 63;
  const int lr = lane & 15, kg = lane >> 4;
  const int q0 = blockIdx.x * 64;
  // first weight buffers issued before staging (overlap with barrier)
  short8 yf[2][4];
  #pragma unroll
  for (int ks=0; ks<4; ks++)
    yf[0][ks] = *(const short8*)(vwt + (size_t)lr*128 + ks*32 + kg*8);
  {
    int row = tid >> 2, c0 = (tid & 3) * 32;
    int q = q0 + row, qy = q / W_, qx = q - qy*W_;
    const float* sp = src + (size_t)q*128 + c0;
    const float* tp = (c0 < 64) ? (py + qy*64 + c0) : (px + qx*64 + (c0 - 64));
    #pragma unroll
    for (int i=0;i<4;i++){
      f32x4 s0 = *(const f32x4*)(sp + i*8), s1 = *(const f32x4*)(sp + i*8 + 4);
      f32x4 t0 = *(const f32x4*)(tp + i*8), t1 = *(const f32x4*)(tp + i*8 + 4);
      u16x8 pa, pq;
      #pragma unroll
      for (int j=0;j<4;j++){
        pa[j] = f2b(s0[j]);        pa[4+j] = f2b(s1[j]);
        pq[j] = f2b(s0[j]+t0[j]);  pq[4+j] = f2b(s1[j]+t1[j]);
      }
      int byte = row*256 + (c0 + i*8)*2;
      *(u16x8*)((char*)a_lds + SWZ(row, byte)) = pa;
      *(u16x8*)((char*)qlds + SWZ(row, byte)) = pq;
    }
  }
  __syncthreads();
  const int qrow = wave*16 + lr;
  short8 xf[4], xq[4];
  #pragma unroll
  for (int ks=0; ks<4; ks++){
    xf[ks] = *(const short8*)((const char*)a_lds + SWZ(qrow, qrow*256 + (ks*32 + kg*8)*2));
    xq[ks] = *(const short8*)((const char*)qlds + SWZ(qrow, qrow*256 + (ks*32 + kg*8)*2));
  }
  f32x4 va[8];
  #pragma unroll
  for (int dt=0; dt<8; dt++) va[dt] = (f32x4){0.f,0.f,0.f,0.f};
  #pragma unroll
  for (int dt=0; dt<8; dt++){
    if (dt < 7){
      const int nr = (dt+1)*16 + lr;
      #pragma unroll
      for (int ks=0; ks<4; ks++)
        yf[(dt+1)&1][ks] = *(const short8*)(vwt + (size_t)nr*128 + ks*32 + kg*8);
    }
    #pragma unroll
    for (int ks=0; ks<4; ks++)
      va[dt] = __builtin_amdgcn_mfma_f32_16x16x32_bf16(xf[ks], yf[dt&1][ks], va[dt], 0, 0, 0);
  }
  f32x4 qa[6];
  #pragma unroll
  for (int nt=0; nt<6; nt++) qa[nt] = (f32x4){0.f,0.f,0.f,0.f};
  short8 of[2][4];
  #pragma unroll
  for (int ks=0; ks<4; ks++)
    of[0][ks] = *(const short8*)(owt + (size_t)lr*128 + ks*32 + kg*8);
  #pragma unroll
  for (int nt=0; nt<6; nt++){
    if (nt < 5){
      const int nr = (nt+1)*16 + lr;
      #pragma unroll
      for (int ks=0; ks<4; ks++)
        of[(nt+1)&1][ks] = *(const short8*)(owt + (size_t)nr*128 + ks*32 + kg*8);
    }
    #pragma unroll
    for (int ks=0; ks<4; ks++)
      qa[nt] = __builtin_amdgcn_mfma_f32_16x16x32_bf16(xq[ks], of[nt&1][ks], qa[nt], 0, 0, 0);
  }
  #pragma unroll
  for (int dt=0; dt<8; dt++){
    float bb = b2f(vb[dt*16 + lr]);
    #pragma unroll
    for (int r=0; r<4; r++){
      int q = q0 + wave*16 + kg*4 + r;
      valbf[(size_t)q*128 + dt*16 + lr] = f2b(va[dt][r] + bb);
    }
  }
  #pragma unroll
  for (int r=0; r<4; r++){
    int q = q0 + wave*16 + kg*4 + r;
    int qy = q / W_, qx = q - qy*W_;
    float qxf = (float)qx, qyf = (float)qy;
    #pragma unroll
    for (int dt=0; dt<4; dt++){
      int n = dt*16 + lr;
      float v = qa[dt][r] + b2f(ob[n]);
      loc[(size_t)q*64 + n] = ((n & 1) ? qyf : qxf) + v;
    }
    #pragma unroll
    for (int d4=0; d4<2; d4++){
      int idx = d4*16 + lr;
      float v = qa[4+d4][r] + b2f(awb[idx]);
      float mx = fmaxf(v, __shfl_xor(v, 1, 64));
      mx = fmaxf(mx, __shfl_xor(mx, 2, 64));
      float e = expf(v - mx);
      float s = e + __shfl_xor(e, 1, 64);
      s = s + __shfl_xor(s, 2, 64);
      awg[(size_t)q*32 + idx] = e / s;
    }
  }
}

// ---------------- out-proj + residual + LN (hoisted + prefetch) ----------
__global__ __launch_bounds__(256) void outln_mfma(const float* __restrict__ A,
    const ushort_t* __restrict__ wt,
    const ushort_t* __restrict__ bias,
    const ushort_t* __restrict__ gs, const ushort_t* __restrict__ gb,
    float* srcio){
  __shared__ ushort_t a_lds[64*128];
  const int tid = threadIdx.x;
  const int wave = tid >> 6, lane = tid & 63;
  const int lr = lane & 15, kg = lane >> 4;
  const int q0 = blockIdx.x * 64;
  short8 yf[2][4];
  #pragma unroll
  for (int ks=0; ks<4; ks++)
    yf[0][ks] = *(const short8*)(wt + (size_t)lr*128 + ks*32 + kg*8);
  {
    int row = tid >> 2, c0 = (tid & 3) * 32;
    const float* sp = A + (size_t)(q0+row)*128 + c0;
    #pragma unroll
    for (int i=0;i<4;i++){
      f32x4 v0 = *(const f32x4*)(sp + i*8);
      f32x4 v1 = *(const f32x4*)(sp + i*8 + 4);
      u16x8 pk;
      #pragma unroll
      for (int j=0;j<4;j++){ pk[j]=f2b(v0[j]); pk[4+j]=f2b(v1[j]); }
      int byte = row*256 + (c0 + i*8)*2;
      *(u16x8*)((char*)a_lds + SWZ(row, byte)) = pk;
    }
  }
  __syncthreads();
  const int qrow = wave*16 + lr;
  short8 xf[4];
  #pragma unroll
  for (int ks=0; ks<4; ks++)
    xf[ks] = *(const short8*)((const char*)a_lds + SWZ(qrow, qrow*256 + (ks*32 + kg*8)*2));
  f32x4 acc[8];
  #pragma unroll
  for (int dt=0; dt<8; dt++) acc[dt] = (f32x4){0.f,0.f,0.f,0.f};
  #pragma unroll
  for (int dt=0; dt<8; dt++){
    if (dt < 7){
      const int nr = (dt+1)*16 + lr;
      #pragma unroll
      for (int ks=0; ks<4; ks++)
        yf[(dt+1)&1][ks] = *(const short8*)(wt + (size_t)nr*128 + ks*32 + kg*8);
    }
    #pragma unroll
    for (int ks=0; ks<4; ks++)
      acc[dt] = __builtin_amdgcn_mfma_f32_16x16x32_bf16(xf[ks], yf[dt&1][ks], acc[dt], 0, 0, 0);
  }
  float g4[8], be4[8], bi4[8];
  #pragma unroll
  for (int dt=0; dt<8; dt++){
    g4[dt] = b2f(gs[dt*16+lr]); be4[dt] = b2f(gb[dt*16+lr]); bi4[dt] = b2f(bias[dt*16+lr]);
  }
  #pragma unroll
  for (int r=0; r<4; r++){
    const int q = q0 + wave*16 + kg*4 + r;
    float vals[8];
    float s1 = 0.f, s2 = 0.f;
    #pragma unroll
    for (int dt=0; dt<8; dt++){
      float v = acc[dt][r] + bi4[dt] + srcio[(size_t)q*128 + dt*16 + lr];
      vals[dt] = v; s1 += v; s2 += v*v;
    }
    #pragma unroll
    for (int m=1; m<16; m<<=1){ s1 += __shfl_xor(s1, m, 64); s2 += __shfl_xor(s2, m, 64); }
    float mean = s1*(1.f/128.f);
    float var  = s2*(1.f/128.f) - mean*mean;
    float inv  = rsqrtf(var + 1e-5f);
    #pragma unroll
    for (int dt=0; dt<8; dt++)
      srcio[(size_t)q*128 + dt*16 + lr] = (vals[dt]-mean)*inv*g4[dt] + be4[dt];
  }
}

// ------------- fused FFN + residual + LN (8 waves, dt-per-wave GEMM2) -------------
__global__ __launch_bounds__(512, 4) void ffn_mfma(
    const ushort_t* __restrict__ w1t,  // [512 n][128 k] bf16
    const ushort_t* __restrict__ b1,
    const ushort_t* __restrict__ w2t,  // [128 n][512 k] bf16
    const ushort_t* __restrict__ b2,
    const ushort_t* __restrict__ gs, const ushort_t* __restrict__ gb,
    float* srcio){
  __shared__ char smem[49152];
  ushort_t* a_lds = (ushort_t*)smem;            // 16KB swizzled
  ushort_t* h_lds = (ushort_t*)(smem + 16384);  // 32KB swizzled
  float* scr = (float*)smem;                    // [64][132] f32 overlay (epilogue)
  const int tid = threadIdx.x;
  const int wave = tid >> 6, lane = tid & 63;
  const int lr = lane & 15, kg = lane >> 4;
  const int q0 = blockIdx.x * 64;
  {
    int row = tid >> 3, c0 = (tid & 7) * 16;
    const float* sp = srcio + (size_t)(q0+row)*128 + c0;
    #pragma unroll
    for (int i=0;i<2;i++){
      f32x4 v0 = *(const f32x4*)(sp + i*8);
      f32x4 v1 = *(const f32x4*)(sp + i*8 + 4);
      u16x8 pk;
      #pragma unroll
      for (int j=0;j<4;j++){ pk[j]=f2b(v0[j]); pk[4+j]=f2b(v1[j]); }
      int byte = row*256 + (c0 + i*8)*2;
      *(u16x8*)((char*)a_lds + SWZ(row, byte)) = pk;
    }
  }
  const int drow = wave*16 + lr;     // GEMM2: this wave's n-rows
  f32x4 accd[4];
  #pragma unroll
  for (int qt=0; qt<4; qt++) accd[qt] = (f32x4){0.f,0.f,0.f,0.f};
  __syncthreads();
  for (int half=0; half<2; half++){
    // batch-issue GEMM1 weights (2 n-tiles) and GEMM2 weights (this wave's row)
    short8 wf[2][4];
    #pragma unroll
    for (int nt=0; nt<2; nt++){
      const int nrow = (half*16 + wave*2 + nt)*16 + lr;
      #pragma unroll
      for (int ks=0; ks<4; ks++)
        wf[nt][ks] = *(const short8*)(w1t + (size_t)nrow*128 + ks*32 + kg*8);
    }
    short8 yg[8];
    #pragma unroll
    for (int ks=0; ks<8; ks++)
      yg[ks] = *(const short8*)(w2t + (size_t)drow*512 + half*256 + ks*32 + kg*8);
    // GEMM1
    #pragma unroll
    for (int nt=0; nt<2; nt++){
      const int ngt = half*16 + wave*2 + nt;
      u16x4 bb = *(const u16x4*)(b1 + ngt*16 + kg*4);
      float bf[4];
      #pragma unroll
      for (int j=0;j<4;j++) bf[j] = b2f(bb[j]);
      #pragma unroll
      for (int qt=0; qt<4; qt++){
        f32x4 acc = (f32x4){0.f,0.f,0.f,0.f};
        const int q = qt*16 + lr;
        #pragma unroll
        for (int ks=0; ks<4; ks++){
          short8 yf = *(const short8*)((const char*)a_lds + SWZ(q, q*256 + (ks*32 + kg*8)*2));
          acc = __builtin_amdgcn_mfma_f32_16x16x32_bf16(wf[nt][ks], yf, acc, 0, 0, 0);
        }
        const int nl = (ngt & 15)*16 + kg*4;
        u16x4 hp;
        #pragma unroll
        for (int r=0;r<4;r++){ float v = acc[r] + bf[r]; hp[r] = f2b(v > 0.f ? v : 0.f); }
        *(u16x4*)((char*)h_lds + SWZ(q, q*512 + nl*2)) = hp;
      }
    }
    __syncthreads();
    // GEMM2: one dt-tile per wave, all 4 q-tiles
    #pragma unroll
    for (int qt=0; qt<4; qt++){
      const int qrow = qt*16 + lr;
      short8 xh[8];
      #pragma unroll
      for (int ks=0; ks<8; ks++)
        xh[ks] = *(const short8*)((const char*)h_lds + SWZ(qrow, qrow*512 + (ks*32 + kg*8)*2));
      #pragma unroll
      for (int ks=0; ks<8; ks++)
        accd[qt] = __builtin_amdgcn_mfma_f32_16x16x32_bf16(xh[ks], yg[ks], accd[qt], 0, 0, 0);
    }
    __syncthreads();
  }
  // dump all partials to f32 scratch [64][132]
  #pragma unroll
  for (int qt=0; qt<4; qt++)
    #pragma unroll
    for (int r=0; r<4; r++)
      scr[(qt*16 + kg*4 + r)*132 + wave*16 + lr] = accd[qt][r];
  __syncthreads();
  // LN: each wave handles 8 q-rows, full-row 64-lane shfl reduce
  {
    const int c = lane*2;
    float bi0 = b2f(b2[c]),  bi1 = b2f(b2[c+1]);
    float g0  = b2f(gs[c]),  g1  = b2f(gs[c+1]);
    float be0 = b2f(gb[c]),  be1 = b2f(gb[c+1]);
    #pragma unroll
    for (int i=0; i<8; i++){
      const int ql = wave*8 + i;
      const size_t qg = (size_t)(q0 + ql)*128 + c;
      f32x2 res = *(const f32x2*)&srcio[qg];
      float v0 = scr[ql*132 + c]     + bi0 + res[0];
      float v1 = scr[ql*132 + c + 1] + bi1 + res[1];
      float s1 = v0 + v1, s2 = v0*v0 + v1*v1;
      #pragma unroll
      for (int m=1; m<64; m<<=1){ s1 += __shfl_xor(s1, m, 64); s2 += __shfl_xor(s2, m, 64); }
      float mean = s1*(1.f/128.f);
      float var  = s2*(1.f/128.f) - mean*mean;
      float inv  = rsqrtf(var + 1e-5f);
      f32x2 outv;
      outv[0] = (v0-mean)*inv*g0 + be0;
      outv[1] = (v1-mean)*inv*g1 + be1;
      *(f32x2*)&srcio[qg] = outv;
    }
  }
}

// ---------------- deformable bilinear sampling (branchless, batched gathers) ----
__global__ __launch_bounds__(256) void sample_kernel(const ushort_t* __restrict__ val,
    const float* __restrict__ loc, const float* __restrict__ awg,
    float* __restrict__ o){
  __shared__ float sl[4][64];
  __shared__ float sa[4][32];
  const int tid = threadIdx.x;
  const int q0 = blockIdx.x * 4;
  sl[0][tid & 255] = loc[(size_t)q0*64 + tid];
  if (tid < 128) sa[0][tid] = awg[(size_t)q0*32 + tid];
  __syncthreads();
  const int ql = tid >> 6, cp = (tid & 63) * 2;
  const int h = cp >> 4;
  float a0 = 0.f, a1 = 0.f;
  #pragma unroll
  for (int p=0;p<4;p++){
    float x = sl[ql][h*8 + p*2];
    float y = sl[ql][h*8 + p*2 + 1];
    float wgt = sa[ql][h*4 + p];
    float x0f = floorf(x), y0f = floorf(y);
    float wx = x - x0f, wy = y - y0f;
    int ix = (int)x0f, iy = (int)y0f;
    int x0c = min(max(ix, 0), W_-1),   x1c = min(max(ix+1, 0), W_-1);
    int y0c = min(max(iy, 0), H_-1),   y1c = min(max(iy+1, 0), H_-1);
    float vx0 = (ix   >= 0 && ix   < W_) ? 1.f : 0.f;
    float vx1 = (ix+1 >= 0 && ix+1 < W_) ? 1.f : 0.f;
    float vy0 = (iy   >= 0 && iy   < H_) ? 1.f : 0.f;
    float vy1 = (iy+1 >= 0 && iy+1 < H_) ? 1.f : 0.f;
    float w00 = (1.f-wx)*(1.f-wy)*vx0*vy0 * wgt;
    float w10 = wx*(1.f-wy)*vx1*vy0 * wgt;
    float w01 = (1.f-wx)*wy*vx0*vy1 * wgt;
    float w11 = wx*wy*vx1*vy1 * wgt;
    unsigned g00 = *(const unsigned*)(val + (size_t)(y0c*W_ + x0c)*128 + cp);
    unsigned g10 = *(const unsigned*)(val + (size_t)(y0c*W_ + x1c)*128 + cp);
    unsigned g01 = *(const unsigned*)(val + (size_t)(y1c*W_ + x0c)*128 + cp);
    unsigned g11 = *(const unsigned*)(val + (size_t)(y1c*W_ + x1c)*128 + cp);
    a0 += w00*b2f((ushort_t)g00) + w10*b2f((ushort_t)g10)
        + w01*b2f((ushort_t)g01) + w11*b2f((ushort_t)g11);
    a1 += w00*b2f((ushort_t)(g00>>16)) + w10*b2f((ushort_t)(g10>>16))
        + w01*b2f((ushort_t)(g01>>16)) + w11*b2f((ushort_t)(g11>>16));
  }
  f32x2 r; r[0] = a0; r[1] = a1;
  *(f32x2*)&o[(size_t)(q0+ql)*128 + cp] = r;
}

// ---------------- outc (hoisted + prefetch): relu -> fp32 [D][Q] ----------
__global__ __launch_bounds__(256) void outc_mfma(const float* __restrict__ A,
    const ushort_t* __restrict__ wt,
    const ushort_t* __restrict__ bias,
    float* __restrict__ outp){
  __shared__ ushort_t a_lds[64*128];
  const int tid = threadIdx.x;
  const int wave = tid >> 6, lane = tid & 63;
  const int lr = lane & 15, kg = lane >> 4;
  const int q0 = blockIdx.x * 64;
  short8 yf[2][4];
  #pragma unroll
  for (int ks=0; ks<4; ks++)
    yf[0][ks] = *(const short8*)(wt + (size_t)lr*128 + ks*32 + kg*8);
  {
    int row = tid >> 2, c0 = (tid & 3) * 32;
    const float* sp = A + (size_t)(q0+row)*128 + c0;
    #pragma unroll
    for (int i=0;i<4;i++){
      f32x4 v0 = *(const f32x4*)(sp + i*8);
      f32x4 v1 = *(const f32x4*)(sp + i*8 + 4);
      u16x8 pk;
      #pragma unroll
      for (int j=0;j<4;j++){ pk[j]=f2b(v0[j]); pk[4+j]=f2b(v1[j]); }
      int byte = row*256 + (c0 + i*8)*2;
      *(u16x8*)((char*)a_lds + SWZ(row, byte)) = pk;
    }
  }
  __syncthreads();
  const int qrow = wave*16 + lr;
  short8 xf[4];
  #pragma unroll
  for (int ks=0; ks<4; ks++)
    xf[ks] = *(const short8*)((const char*)a_lds + SWZ(qrow, qrow*256 + (ks*32 + kg*8)*2));
  f32x4 acc[8];
  #pragma unroll
  for (int dt=0; dt<8; dt++) acc[dt] = (f32x4){0.f,0.f,0.f,0.f};
  #pragma unroll
  for (int dt=0; dt<8; dt++){
    if (dt < 7){
      const int nr = (dt+1)*16 + lr;
      #pragma unroll
      for (int ks=0; ks<4; ks++)
        yf[(dt+1)&1][ks] = *(const short8*)(wt + (size_t)nr*128 + ks*32 + kg*8);
    }
    #pragma unroll
    for (int ks=0; ks<4; ks++)
      acc[dt] = __builtin_amdgcn_mfma_f32_16x16x32_bf16(xf[ks], yf[dt&1][ks], acc[dt], 0, 0, 0);
  }
  #pragma unroll
  for (int dt=0; dt<8; dt++){
    float bb = b2f(bias[dt*16 + lr]);
    #pragma unroll
    for (int r=0; r<4; r++){
      int q = q0 + wave*16 + kg*4 + r;
      float v = acc[dt][r] + bb;
      v = v > 0.f ? v : 0.f;
      outp[(size_t)(dt*16 + lr)*Q_TOT + q] = v;
    }
  }
}

extern "C" void kernel_launch(void* const* d_in, const int* in_sizes, int n_in,
                              void* d_out, int out_size, void* d_ws, size_t ws_size,
                              hipStream_t stream){
  const float* x = (const float*)d_in[0];

  float* src = (float*)d_ws;
  float* loc = src + (size_t)Q_TOT*128;
  float* aw  = loc + (size_t)Q_TOT*64;
  float* o   = aw  + (size_t)Q_TOT*32;
  ushort_t* valbf = (ushort_t*)(o + (size_t)Q_TOT*128);
  ushort_t* wbf   = valbf + (size_t)Q_TOT*128;
  ushort_t* tbase = wbf + 615072;
  float* postab = (float*)(tbase + 528384);
  float* pytab = postab;
  float* pxtab = postab + 120*64;

  const ushort_t* mw     = wbf + 0;
  const ushort_t* mb     = wbf + 65536;
  const ushort_t* off_b  = wbf + 90240;
  const ushort_t* aw_b   = wbf + 102720;
  const ushort_t* val_b  = wbf + 151968;
  const ushort_t* out_b  = wbf + 201504;
  const ushort_t* n1_s   = wbf + 201888;
  const ushort_t* n1_b   = wbf + 202272;
  const ushort_t* l1_b   = wbf + 399264;
  const ushort_t* l2_b   = wbf + 597408;
  const ushort_t* n2_s   = wbf + 597792;
  const ushort_t* n2_b   = wbf + 598176;
  const ushort_t* outc_w = wbf + 598560;
  const ushort_t* outc_b = wbf + 614944;
  const ushort_t* val_wt = tbase + 0;
  const ushort_t* out_wt = tbase + 49152;
  const ushort_t* l1_wt  = tbase + 98304;
  const ushort_t* l2_wt  = tbase + 294912;
  const ushort_t* oaw_t  = tbase + 491520;

  cvt_kernel<<<(CVT_TOT+255)/256, 256, 0, stream>>>(
      (const float*)d_in[1],  (const float*)d_in[2],  (const float*)d_in[3],
      (const float*)d_in[4],  (const float*)d_in[5],  (const float*)d_in[6],
      (const float*)d_in[7],  (const float*)d_in[8],  (const float*)d_in[9],
      (const float*)d_in[10], (const float*)d_in[11], (const float*)d_in[12],
      (const float*)d_in[13], (const float*)d_in[14], (const float*)d_in[15],
      (const float*)d_in[16], (const float*)d_in[17], (const float*)d_in[18],
      (const float*)d_in[19], (const float*)d_in[20], wbf);
  cvtT_kernel<<<CVTT_TOT/256, 256, 0, stream>>>(
      (const float*)d_in[7], (const float*)d_in[9],
      (const float*)d_in[13], (const float*)d_in[15],
      (const float*)d_in[3], (const float*)d_in[5], tbase);
  postab_kernel<<<120, 256, 0, stream>>>(postab);

  merge_mfma<<<Q_TOT/64, 256, 0, stream>>>(x, mw, mb, src);
  for (int l = 0; l < 3; l++){
    qv_mfma<<<Q_TOT/64, 256, 0, stream>>>(src, pytab, pxtab,
        oaw_t + (size_t)l*96*128, off_b + (size_t)l*64, aw_b + (size_t)l*32,
        val_wt + (size_t)l*128*128, val_b + (size_t)l*128,
        loc, aw, valbf);
    sample_kernel<<<Q_TOT/4, 256, 0, stream>>>(valbf, loc, aw, o);
    outln_mfma<<<Q_TOT/64, 256, 0, stream>>>(o,
        out_wt + (size_t)l*128*128, out_b + (size_t)l*128,
        n1_s + (size_t)l*128, n1_b + (size_t)l*128, src);
    ffn_mfma<<<Q_TOT/64, 512, 0, stream>>>(
        l1_wt + (size_t)l*512*128, l1_b + (size_t)l*512,
        l2_wt + (size_t)l*128*512, l2_b + (size_t)l*128,
        n2_s + (size_t)l*128, n2_b + (size_t)l*128, src);
  }
  outc_mfma<<<Q_TOT/64, 256, 0, stream>>>(src, outc_w, outc_b, (float*)d_out);
}